// Round 12
// baseline (657.053 us; speedup 1.0000x reference)
//
#include <hip/hip_runtime.h>
#include <cstdint>

#define B 16
#define N 262144
#define PRE 6000
#define KOUT 1000
#define MW 94            // 64-bit mask words per row (6016 bits >= 6000)
#define CW 40            // fast-path column words: rows 0..2559
#define MAXP 16          // max Jacobi passes before falling back
#define NBIN 2049
#define IMGMAX 511.0f
#define NMS_TH 0.7f

typedef unsigned int u32;
typedef unsigned long long u64;

// ---- workspace layout (bytes) ----
// mask is COLUMN-MAJOR: mask[img][cw][row], cw=0..93, row=0..5999.
#define OFF_MASK  0ull                    // 16*94*6000*8         = 72,192,000
#define OFF_SEL   72192000ull             // 16*16384*8           =  2,097,152
#define OFF_BOX   74289152ull             // 16*6016*16           =  1,540,096
#define OFF_VAL   75829248ull             // 16*96*8              =     12,288
#define OFF_HIST  75841536ull             // 16*2052*4            =    131,328
#define OFF_T     75972864ull             // 16*4                 =         64
#define OFF_CNT   75972928ull             // 16*2*4               =        128
#define OFF_FLAG  75973056ull             // 16*4                 =         64
#define WS_NEED   75973120ull
// memset region each call: OFF_VAL .. end = 143,872 bytes

// Box decode — mirrors reference op order; contraction off so we don't fuse
// mul+add where XLA doesn't (keep/valid comparisons must match bit-for-bit).
__device__ __forceinline__ void box_from(const float4 a, const float4 d,
    float& x1, float& y1, float& x2, float& y2, bool& valid) {
#pragma clang fp contract(off)
  float w  = a.z - a.x;
  float h  = a.w - a.y;
  float cx = a.x + 0.5f * w;
  float cy = a.y + 0.5f * h;
  cx = cx + d.x * w;
  cy = cy + d.y * h;
  w = w * expf(d.z);
  h = h * expf(d.w);
  x1 = cx - 0.5f * w;
  y1 = cy - 0.5f * h;
  x2 = cx + 0.5f * w;
  y2 = cy + 0.5f * h;
  x1 = fminf(fmaxf(x1, 0.0f), IMGMAX);
  y1 = fminf(fmaxf(y1, 0.0f), IMGMAX);
  x2 = fminf(fmaxf(x2, 0.0f), IMGMAX);
  y2 = fminf(fmaxf(y2, 0.0f), IMGMAX);
  valid = ((x2 - x1) >= 16.0f) && ((y2 - y1) >= 16.0f);
}

// IoU > 0.7 decision, bit-exact vs IEEE div: fast path uses v_rcp (<=2ulp);
// only lanes with |qa-0.7| <= 1e-4 (P ~ 1e-5) take the exact-div path under
// exec mask. rcp error near 0.7 is ~2e-7 — 500x inside the guard.
__device__ __forceinline__ bool iou_gt(float inter, float denom) {
  float qa = inter * __builtin_amdgcn_rcpf(denom);
  if (__builtin_expect(fabsf(qa - NMS_TH) <= 1e-4f, 0))
    return (inter / denom) > NMS_TH;
  return qa > NMS_TH;
}

// K1: per-image score histogram, grid (256, B) — full-machine decode.
// LDS histogram + nonzero-guarded no-return atomic merge.
// Block x==0 also zeroes boxes rows 6000..6015.
__global__ void k_hist(const float4* __restrict__ anch, const float2* __restrict__ probs,
                       const float4* __restrict__ delt, u32* __restrict__ hist,
                       float4* __restrict__ boxes) {
  __shared__ u32 sh[NBIN];
  int t = threadIdx.x;
  int img = blockIdx.y;
  if (blockIdx.x == 0 && t < 16)
    boxes[(size_t)img * 6016 + 6000 + t] = make_float4(0.f, 0.f, 0.f, 0.f);
  for (int p = t; p < NBIN; p += 256) sh[p] = 0;
  __syncthreads();
  int base = blockIdx.x * 1024;
  for (int r = 0; r < 4; r++) {
    int i = base + r * 256 + t;
    float4 a = anch[i];
    float4 d = delt[(size_t)img * N + i];
    float s = probs[(size_t)img * N + i].y;
    float x1, y1, x2, y2; bool valid;
    box_from(a, d, x1, y1, x2, y2, valid);
    int bin = valid ? (1 + min(2047, (int)(s * 2048.0f))) : 0;
    atomicAdd(&sh[bin], 1u);
  }
  __syncthreads();
  for (int p = t; p < NBIN; p += 256)
    if (sh[p]) atomicAdd(&hist[img * 2052 + p], sh[p]);
}

// K2: T = max bin b (over valid bins 1..2048) with suffix_count(b) >= PRE.
__global__ void k_thresh(const u32* __restrict__ hist, int* __restrict__ Tarr) {
  int img = blockIdx.x;
  int l = threadIdx.x;                       // 64 lanes
  const u32* hb = hist + img * 2052;
  u32 v[32];
  u32 csum = 0;
#pragma unroll
  for (int k = 0; k < 32; k++) { v[k] = hb[l * 32 + 1 + k]; csum += v[k]; }
  u32 sfx = csum;                            // suffix-inclusive over lanes >= l
  for (int off = 1; off < 64; off <<= 1) {
    u32 tv = __shfl_down(sfx, off);
    if (l + off < 64) sfx += tv;
  }
  u32 excl = sfx - csum;
  if (l == 0 && sfx < PRE) Tarr[img] = 0;    // degenerate: < PRE valid boxes
  if (excl < PRE && sfx >= PRE) {            // exactly one lane
    u32 acc = excl; int T = 0;
#pragma unroll
    for (int k = 31; k >= 0; k--) { acc += v[k]; if (acc >= PRE) { T = l * 32 + 1 + k; break; } }
    Tarr[img] = T;
  }
}

// K3: compact candidates. Block-local LDS aggregation; ONE global atomic per
// block per list. sel order nondeterministic; unique keys + exact k_rank ->
// deterministic final output.
__global__ void k_compact(const float4* __restrict__ anch, const float2* __restrict__ probs,
                          const float4* __restrict__ delt, const int* __restrict__ Tarr,
                          u64* __restrict__ sel, u32* __restrict__ cnt) {
  __shared__ u64 buf[1024];
  __shared__ u32 c0, c1, base0, base1;
  int t = threadIdx.x, img = blockIdx.y;
  if (t == 0) { c0 = 0; c1 = 0; }
  __syncthreads();
  int T = Tarr[img];
  int base = blockIdx.x * 1024;
  for (int r = 0; r < 4; r++) {
    int i = base + r * 256 + t;
    float4 a = anch[i];
    float4 d = delt[(size_t)img * N + i];
    float s = probs[(size_t)img * N + i].y;
    float x1, y1, x2, y2; bool valid;
    box_from(a, d, x1, y1, x2, y2, valid);
    int bin = valid ? (1 + min(2047, (int)(s * 2048.0f))) : 0;
    if (bin >= T) {
      u32 u = valid ? (__float_as_uint(s) | 0x80000000u) : 0u;
      u64 key = ((u64)u << 32) | (u64)(0xFFFFFFFFu - (u32)i);
      if (bin > T) { u32 p = atomicAdd(&c0, 1u); buf[p] = key; }
      else         { u32 p = atomicAdd(&c1, 1u); buf[1023 - p] = key; }
    }
  }
  __syncthreads();
  if (t == 0 && c0) base0 = atomicAdd(&cnt[img * 2 + 0], c0);
  if (t == 1 && c1) base1 = atomicAdd(&cnt[img * 2 + 1], c1);
  __syncthreads();
  u64* sb = sel + (size_t)img * 16384;
  for (u32 p = t; p < c0; p += 256) {
    u32 dpos = base0 + p;
    if (dpos < 8192u) sb[dpos] = buf[p];
  }
  for (u32 p = t; p < c1; p += 256) {
    u32 dpos = base1 + p;
    if (dpos < 8192u) sb[8192 + dpos] = buf[1023 - p];
  }
}

// K4: exact pairwise RANK. Keys unique -> rank(i) = #{j: key_j > key_i};
// sorted[rank]=key IS the descending stable sort. j-tile staged in LDS,
// read broadcast. rank < PRE threads decode box + scatter + validw atomicOr.
__global__ void k_rank(const u64* __restrict__ sel, const u32* __restrict__ cnt,
                       const float4* __restrict__ anch, const float4* __restrict__ delt,
                       float4* __restrict__ boxes, u64* __restrict__ validw) {
  __shared__ u64 sh[1024];
  int t = threadIdx.x, img = blockIdx.y;
  u32 e0 = min(cnt[img * 2 + 0], 8192u);
  u32 e1 = min(cnt[img * 2 + 1], 8192u);
  u32 M = e0 + e1;
  if (blockIdx.x * 256u >= M) return;        // empty block, no syncthreads run
  const u64* sb = sel + (size_t)img * 16384;
  u32 ci = blockIdx.x * 256u + (u32)t;
  bool have = ci < M;
  u64 mykey = 0ull;
  if (have) mykey = (ci < e0) ? sb[ci] : sb[8192 + (ci - e0)];
  u32 rank = 0;
  for (u32 jb = 0; jb < M; jb += 1024) {
    u32 tl = min(1024u, M - jb);
    __syncthreads();
    for (u32 p = t; p < tl; p += 256) {
      u32 j = jb + p;
      sh[p] = (j < e0) ? sb[j] : sb[8192 + (j - e0)];
    }
    __syncthreads();
    if (have) {
      u32 full = tl & ~3u;
      for (u32 p = 0; p < full; p += 4) {
        rank += (sh[p]     > mykey);
        rank += (sh[p + 1] > mykey);
        rank += (sh[p + 2] > mykey);
        rank += (sh[p + 3] > mykey);
      }
      for (u32 p = full; p < tl; p++) rank += (sh[p] > mykey);
    }
  }
  if (have && rank < PRE) {
    u32 u  = (u32)(mykey >> 32);
    u32 gi = 0xFFFFFFFFu - (u32)(mykey & 0xFFFFFFFFull);
    float4 a = anch[gi];
    float4 d = delt[(size_t)img * N + gi];
    float x1, y1, x2, y2; bool valid;
    box_from(a, d, x1, y1, x2, y2, valid);
    boxes[(size_t)img * 6016 + rank] = make_float4(x1, y1, x2, y2);
    if (u != 0u)
      atomicOr(&validw[img * 96 + (rank >> 6)], 1ull << (rank & 63));
  }
}

// K5a: IoU suppression bitmask, FAST REGION ONLY: column words 0..CW-1,
// rows < CW*64. COLUMN-MAJOR store: wave = one coalesced 512B store.
__global__ void k_mask(const float4* __restrict__ boxes, u64* __restrict__ mask) {
  __shared__ float4 cbox[4][64];
  __shared__ float  carea[4][64];
  int t = threadIdx.x;
  int rl = t & 63, g = t >> 6;
  int rb = blockIdx.x, img = blockIdx.y;     // rb in [0, CW)
  const float4* bb = boxes + (size_t)img * 6016;
  int r = rb * 64 + rl;
  float4 rx = bb[r];
  float ra = (rx.z - rx.x) * (rx.w - rx.y);
  u64* mimg = mask + (size_t)img * 94 * 6000;
  int jmax = (CW - rb + 3) >> 2;
  for (int j = 0; j < jmax; j++) {
    int cb = rb + g + 4 * j;
    bool act = cb < CW;
    __syncthreads();
    if (act) {
      float4 c = bb[cb * 64 + rl];
      cbox[g][rl] = c;
      carea[g][rl] = (c.z - c.x) * (c.w - c.y);
    }
    __syncthreads();
    if (act) {
#pragma clang fp contract(off)
      u64 bits = 0ull;
      for (int m = 0; m < 64; m++) {
        float4 cx = cbox[g][m];
        float xx1 = fmaxf(rx.x, cx.x);
        float yy1 = fmaxf(rx.y, cx.y);
        float xx2 = fminf(rx.z, cx.z);
        float yy2 = fminf(rx.w, cx.w);
        float inter = fmaxf(xx2 - xx1, 0.0f) * fmaxf(yy2 - yy1, 0.0f);
        float denom = ra + carea[g][m] - inter + 1e-9f;
        int c_j = cb * 64 + m;
        if (iou_gt(inter, denom) && c_j != r) bits |= (1ull << m);
      }
      mimg[(size_t)cb * 6000 + r] = bits;
    }
  }
}

// K5b: rescue — remaining triangle (cb >= max(rb,CW)). No-op when the fast
// scan succeeded for this image (okf[img]==1, the expected case).
__global__ void k_mask_rest(const float4* __restrict__ boxes, u64* __restrict__ mask,
                            const u32* __restrict__ okf) {
  int rb = blockIdx.x, img = blockIdx.y;
  if (okf[img]) return;
  __shared__ float4 cbox[4][64];
  __shared__ float  carea[4][64];
  int t = threadIdx.x;
  int rl = t & 63, g = t >> 6;
  const float4* bb = boxes + (size_t)img * 6016;
  int r = rb * 64 + rl;
  float4 rx = bb[r];
  float ra = (rx.z - rx.x) * (rx.w - rx.y);
  u64* mimg = mask + (size_t)img * 94 * 6000;
  int cb0 = rb > CW ? rb : CW;
  int jmax = (94 - cb0 + 3) >> 2;
  for (int j = 0; j < jmax; j++) {
    int cb = cb0 + g + 4 * j;
    bool act = cb < 94;
    __syncthreads();
    if (act) {
      float4 c = bb[cb * 64 + rl];
      cbox[g][rl] = c;
      carea[g][rl] = (c.z - c.x) * (c.w - c.y);
    }
    __syncthreads();
    if (act) {
#pragma clang fp contract(off)
      u64 bits = 0ull;
      for (int m = 0; m < 64; m++) {
        float4 cx = cbox[g][m];
        float xx1 = fmaxf(rx.x, cx.x);
        float yy1 = fmaxf(rx.y, cx.y);
        float xx2 = fminf(rx.z, cx.z);
        float yy2 = fminf(rx.w, cx.w);
        float inter = fmaxf(xx2 - xx1, 0.0f) * fmaxf(yy2 - yy1, 0.0f);
        float denom = ra + carea[g][m] - inter + 1e-9f;
        int c_j = cb * 64 + m;
        if (iou_gt(inter, denom) && c_j != r) bits |= (1ull << m);
      }
      if (r < PRE) mimg[(size_t)cb * 6000 + r] = bits;
    }
  }
}

// K6a: JACOBI FIXPOINT NMS (replaces the serial greedy scan — 5 designs of
// which all hit >=138us because memory traffic sat on the serial keep chain).
// greedy NMS = unique fixpoint of kept(j)=valid(j) && !exists i<j: kept(i) &&
// edge(i,j) (induction on j). Iterate kept_{k+1}=F(kept_k) from kept_0=valid
// with FULLY PARALLEL passes; on next==kept the fixpoint is VERIFIED => exact.
// Not converged in MAXP passes or <KOUT keeps => okf=0 => exact rescue path.
//  supp phase: wave owns target chunks cw%4==w; lane l accumulates
//    acc |= kept[sc] bit l ? mask[cw][sc*64+l] : 0 over sc<cw (coalesced),
//    then one shfl-OR-tree. next phase: diag word (lower-triangle bits,
//    current kept) + __ballot reassembles the word. 4 barriers/pass.
__global__ void __launch_bounds__(256, 1) k_scan_fast(
    const u64* __restrict__ mask, const u64* __restrict__ validw,
    const float4* __restrict__ boxes, float4* __restrict__ out,
    u32* __restrict__ okf) {
  __shared__ u64 kept[CW], nxt[CW], supp[CW], vw[CW];
  __shared__ u32 chg, totk;
  __shared__ u32 basep[CW];
  __shared__ unsigned short list[KOUT];
  int t = threadIdx.x;
  int l = t & 63, w = t >> 6;                // lane, wave(0..3)
  int img = blockIdx.x;
  const u64* mimg = mask + (size_t)img * 94 * 6000;
  if (t < CW) { u64 v = validw[img * 96 + t]; vw[t] = v; kept[t] = v; }
  __syncthreads();
  bool conv = false;
  for (int pass = 0; pass < MAXP && !conv; pass++) {
    // supp[cw] = OR over kept rows in strictly-earlier chunks
    for (int cw = w; cw < CW; cw += 4) {
      u64 acc = 0ull;
      const u64* colc = mimg + (size_t)cw * 6000;
      for (int sc = 0; sc < cw; sc++) {
        u64 kv = kept[sc];
        acc |= ((kv >> l) & 1ull) ? colc[sc * 64 + l] : 0ull;
      }
#pragma unroll
      for (int off = 32; off >= 1; off >>= 1) acc |= __shfl_xor(acc, off);
      if (l == 0) supp[cw] = acc;
    }
    __syncthreads();
    // next[rb]: per-lane bit = valid && !supp && !(diag & kept & lower-mask)
    for (int rb = w; rb < CW; rb += 4) {
      u64 diag = mimg[(size_t)rb * 6000 + rb * 64 + l];
      u64 kv = kept[rb];
      bool bit = (((vw[rb] >> l) & 1ull) != 0ull) &&
                 (((supp[rb] >> l) & 1ull) == 0ull) &&
                 ((diag & kv & ((1ull << l) - 1ull)) == 0ull);
      u64 word = __ballot(bit);
      if (l == 0) nxt[rb] = word;
    }
    __syncthreads();
    if (t == 0) chg = 0;
    __syncthreads();
    if (t < CW && nxt[t] != kept[t]) atomicOr(&chg, 1u);
    __syncthreads();
    if (t < CW) kept[t] = nxt[t];
    conv = (chg == 0);
    __syncthreads();
  }
  // prefix popcount (wave 0) -> base positions + total
  if (w == 0) {
    u64 kw = (l < CW) ? kept[l] : 0ull;
    u32 pc = (u32)__popcll(kw);
    u32 pre = pc;
    for (int off = 1; off < 64; off <<= 1) {
      u32 v2 = __shfl_up(pre, off);
      if (l >= off) pre += v2;
    }
    if (l < CW) basep[l] = pre - pc;
    if (l == 63) totk = pre;
  }
  __syncthreads();
  bool okimg = conv && (totk >= KOUT);       // uniform across block
  if (t == 0) okf[img] = okimg ? 1u : 0u;
  if (!okimg) return;                        // rescue path takes over
  if (t < CW) {                              // expand kept bits -> ordered list
    u32 b = basep[t];
    u64 word = kept[t];
    while (word) {
      int j = (int)__ffsll(word) - 1;
      word &= word - 1;
      if (b < KOUT) list[b] = (unsigned short)(t * 64 + j);
      b++;
    }
  }
  __syncthreads();
  for (int p = t; p < KOUT; p += 256)
    out[(size_t)img * KOUT + p] = boxes[(size_t)img * 6016 + list[p]];
}

// K6b: full-depth rescue scan (94 words, rows 0..5999). No-op when fast
// scan succeeded. Identical semantics to the reference NMS.
__global__ void k_scan_full(const u64* __restrict__ mask, const u64* __restrict__ validw,
                            const float4* __restrict__ boxes, float4* __restrict__ out,
                            const u32* __restrict__ okf) {
  int img = blockIdx.x;
  if (okf[img]) return;
  __shared__ unsigned short kept[KOUT];
  int l = threadIdx.x;
  const u64* vw = validw + img * 96;
  u64 r0 = ~vw[l];
  u64 r1 = (l < MW - 64) ? ~vw[64 + l] : ~0ull;
  const u64* c0p = mask + ((size_t)img * 94 + l) * 6000;
  const u64* c1p = mask + ((size_t)img * 94 + (l < MW - 64 ? 64 + l : 0)) * 6000;

  u64 ca[16], cb[16], na[16], nb2[16];
#pragma unroll
  for (int k = 0; k < 16; k++) {
    ca[k] = c0p[k];
    cb[k] = (l < MW - 64) ? c1p[k] : 0ull;
  }
  int cnt = 0; bool done = false;
  for (int base = 0; base < PRE; base += 16) {
#pragma unroll
    for (int k = 0; k < 16; k++) {
      int rr = base + 16 + k;
      if (rr < PRE) {
        na[k]  = c0p[rr];
        nb2[k] = (l < MW - 64) ? c1p[rr] : 0ull;
      } else { na[k] = 0ull; nb2[k] = 0ull; }
    }
#pragma unroll
    for (int k = 0; k < 16; k++) {
      if (!done) {
        int i = base + k;
        int w = i >> 6;
        u64 wv = (w < 64) ? __shfl(r0, w) : __shfl(r1, w - 64);
        if (!((wv >> (i & 63)) & 1ull)) {
          if (l == 0 && cnt < KOUT) kept[cnt] = (unsigned short)i;
          cnt++;
          r0 |= (l >= w)        ? ca[k] : 0ull;
          r1 |= ((64 + l) >= w) ? cb[k] : 0ull;
          if (cnt >= KOUT) done = true;
        }
      }
    }
    if (done) break;
#pragma unroll
    for (int k = 0; k < 16; k++) { ca[k] = na[k]; cb[k] = nb2[k]; }
  }
  __syncthreads();
  for (int p = l; p < KOUT; p += 64) {
    float4 v = make_float4(0.f, 0.f, 0.f, 0.f);
    if (p < cnt) v = boxes[(size_t)img * 6016 + kept[p]];
    out[(size_t)img * KOUT + p] = v;
  }
}

extern "C" void kernel_launch(void* const* d_in, const int* in_sizes, int n_in,
                              void* d_out, int out_size, void* d_ws, size_t ws_size,
                              hipStream_t stream) {
  const float4* anch  = (const float4*)d_in[0];
  const float2* probs = (const float2*)d_in[1];
  const float4* delt  = (const float4*)d_in[2];
  float4* out = (float4*)d_out;
  char* ws = (char*)d_ws;
  (void)in_sizes; (void)n_in;

  if (ws_size < WS_NEED) {  // not enough scratch: write zeros, bail cleanly
    (void)hipMemsetAsync(d_out, 0, (size_t)out_size * sizeof(float), stream);
    return;
  }

  u64* mask    = (u64*)(ws + OFF_MASK);
  u64* sel     = (u64*)(ws + OFF_SEL);
  float4* bxs  = (float4*)(ws + OFF_BOX);
  u64* validw  = (u64*)(ws + OFF_VAL);
  u32* hist    = (u32*)(ws + OFF_HIST);
  int* Tarr    = (int*)(ws + OFF_T);
  u32* cnt     = (u32*)(ws + OFF_CNT);
  u32* okf     = (u32*)(ws + OFF_FLAG);

  // zero validw + hist + Tarr + cnt + flag every call (contiguous tail)
  (void)hipMemsetAsync(ws + OFF_VAL, 0, 143872, stream);

  dim3 g1(256, B);
  k_hist<<<g1, 256, 0, stream>>>(anch, probs, delt, hist, bxs);
  k_thresh<<<B, 64, 0, stream>>>(hist, Tarr);
  k_compact<<<g1, 256, 0, stream>>>(anch, probs, delt, Tarr, sel, cnt);
  dim3 g4(64, B);
  k_rank<<<g4, 256, 0, stream>>>(sel, cnt, anch, delt, bxs, validw);
  dim3 g5(CW, B);
  k_mask<<<g5, 256, 0, stream>>>(bxs, mask);
  k_scan_fast<<<B, 256, 0, stream>>>(mask, validw, bxs, out, okf);
  dim3 g5b(94, B);
  k_mask_rest<<<g5b, 256, 0, stream>>>(bxs, mask, okf);
  k_scan_full<<<B, 64, 0, stream>>>(mask, validw, bxs, out, okf);
}

// Round 13
// 538.998 us; speedup vs baseline: 1.2190x; 1.2190x over previous
//
#include <hip/hip_runtime.h>
#include <cstdint>

#define B 16
#define N 262144
#define PRE 6000
#define KOUT 1000
#define MW 94            // 64-bit mask words per row (6016 bits >= 6000)
#define CW 40            // fast-path column words: rows 0..2559
#define ECAP 4096        // per-image edge-list capacity
#define NBIN 2049
#define IMGMAX 511.0f
#define NMS_TH 0.7f

typedef unsigned int u32;
typedef unsigned long long u64;

// ---- workspace layout (bytes) ----
// mask is COLUMN-MAJOR: mask[img][cw][row], cw=0..93, row=0..5999.
#define OFF_MASK  0ull                    // 16*94*6000*8         = 72,192,000
#define OFF_SEL   72192000ull             // 16*16384*8           =  2,097,152
#define OFF_BOX   74289152ull             // 16*6016*16           =  1,540,096
#define OFF_VAL   75829248ull             // 16*96*8              =     12,288
#define OFF_HIST  75841536ull             // 16*2052*4            =    131,328
#define OFF_T     75972864ull             // 16*4                 =         64
#define OFF_CNT   75972928ull             // 16*2*4               =        128
#define OFF_FLAG  75973056ull             // 16*4                 =         64
#define OFF_ECNT  75973120ull             // 16*4                 =         64
#define OFF_EDG   75973184ull             // 16*4096*4            =    262,144
#define WS_NEED   76235328ull
// memset region each call: OFF_VAL .. OFF_ECNT+64 = 143,936 bytes

// Box decode — mirrors reference op order; contraction off so we don't fuse
// mul+add where XLA doesn't (keep/valid comparisons must match bit-for-bit).
__device__ __forceinline__ void box_from(const float4 a, const float4 d,
    float& x1, float& y1, float& x2, float& y2, bool& valid) {
#pragma clang fp contract(off)
  float w  = a.z - a.x;
  float h  = a.w - a.y;
  float cx = a.x + 0.5f * w;
  float cy = a.y + 0.5f * h;
  cx = cx + d.x * w;
  cy = cy + d.y * h;
  w = w * expf(d.z);
  h = h * expf(d.w);
  x1 = cx - 0.5f * w;
  y1 = cy - 0.5f * h;
  x2 = cx + 0.5f * w;
  y2 = cy + 0.5f * h;
  x1 = fminf(fmaxf(x1, 0.0f), IMGMAX);
  y1 = fminf(fmaxf(y1, 0.0f), IMGMAX);
  x2 = fminf(fmaxf(x2, 0.0f), IMGMAX);
  y2 = fminf(fmaxf(y2, 0.0f), IMGMAX);
  valid = ((x2 - x1) >= 16.0f) && ((y2 - y1) >= 16.0f);
}

// IoU > 0.7 decision, bit-exact vs IEEE div: fast path uses v_rcp (<=2ulp);
// only lanes with |qa-0.7| <= 1e-4 (P ~ 1e-5) take the exact-div path under
// exec mask. rcp error near 0.7 is ~2e-7 — 500x inside the guard.
__device__ __forceinline__ bool iou_gt(float inter, float denom) {
  float qa = inter * __builtin_amdgcn_rcpf(denom);
  if (__builtin_expect(fabsf(qa - NMS_TH) <= 1e-4f, 0))
    return (inter / denom) > NMS_TH;
  return qa > NMS_TH;
}

__device__ __forceinline__ u64 readlane64(u64 v, int lane) {
  u32 lo = (u32)__builtin_amdgcn_readlane((int)(u32)v, lane);
  u32 hi = (u32)__builtin_amdgcn_readlane((int)(u32)(v >> 32), lane);
  return ((u64)hi << 32) | (u64)lo;
}

// K1: per-image score histogram, grid (256, B) — full-machine decode.
__global__ void k_hist(const float4* __restrict__ anch, const float2* __restrict__ probs,
                       const float4* __restrict__ delt, u32* __restrict__ hist,
                       float4* __restrict__ boxes) {
  __shared__ u32 sh[NBIN];
  int t = threadIdx.x;
  int img = blockIdx.y;
  if (blockIdx.x == 0 && t < 16)
    boxes[(size_t)img * 6016 + 6000 + t] = make_float4(0.f, 0.f, 0.f, 0.f);
  for (int p = t; p < NBIN; p += 256) sh[p] = 0;
  __syncthreads();
  int base = blockIdx.x * 1024;
  for (int r = 0; r < 4; r++) {
    int i = base + r * 256 + t;
    float4 a = anch[i];
    float4 d = delt[(size_t)img * N + i];
    float s = probs[(size_t)img * N + i].y;
    float x1, y1, x2, y2; bool valid;
    box_from(a, d, x1, y1, x2, y2, valid);
    int bin = valid ? (1 + min(2047, (int)(s * 2048.0f))) : 0;
    atomicAdd(&sh[bin], 1u);
  }
  __syncthreads();
  for (int p = t; p < NBIN; p += 256)
    if (sh[p]) atomicAdd(&hist[img * 2052 + p], sh[p]);
}

// K2: T = max bin b (over valid bins 1..2048) with suffix_count(b) >= PRE.
__global__ void k_thresh(const u32* __restrict__ hist, int* __restrict__ Tarr) {
  int img = blockIdx.x;
  int l = threadIdx.x;                       // 64 lanes
  const u32* hb = hist + img * 2052;
  u32 v[32];
  u32 csum = 0;
#pragma unroll
  for (int k = 0; k < 32; k++) { v[k] = hb[l * 32 + 1 + k]; csum += v[k]; }
  u32 sfx = csum;                            // suffix-inclusive over lanes >= l
  for (int off = 1; off < 64; off <<= 1) {
    u32 tv = __shfl_down(sfx, off);
    if (l + off < 64) sfx += tv;
  }
  u32 excl = sfx - csum;
  if (l == 0 && sfx < PRE) Tarr[img] = 0;    // degenerate: < PRE valid boxes
  if (excl < PRE && sfx >= PRE) {            // exactly one lane
    u32 acc = excl; int T = 0;
#pragma unroll
    for (int k = 31; k >= 0; k--) { acc += v[k]; if (acc >= PRE) { T = l * 32 + 1 + k; break; } }
    Tarr[img] = T;
  }
}

// K3: compact candidates. Block-local LDS aggregation; ONE global atomic per
// block per list. sel order nondeterministic; unique keys + exact k_rank ->
// deterministic final output.
__global__ void k_compact(const float4* __restrict__ anch, const float2* __restrict__ probs,
                          const float4* __restrict__ delt, const int* __restrict__ Tarr,
                          u64* __restrict__ sel, u32* __restrict__ cnt) {
  __shared__ u64 buf[1024];
  __shared__ u32 c0, c1, base0, base1;
  int t = threadIdx.x, img = blockIdx.y;
  if (t == 0) { c0 = 0; c1 = 0; }
  __syncthreads();
  int T = Tarr[img];
  int base = blockIdx.x * 1024;
  for (int r = 0; r < 4; r++) {
    int i = base + r * 256 + t;
    float4 a = anch[i];
    float4 d = delt[(size_t)img * N + i];
    float s = probs[(size_t)img * N + i].y;
    float x1, y1, x2, y2; bool valid;
    box_from(a, d, x1, y1, x2, y2, valid);
    int bin = valid ? (1 + min(2047, (int)(s * 2048.0f))) : 0;
    if (bin >= T) {
      u32 u = valid ? (__float_as_uint(s) | 0x80000000u) : 0u;
      u64 key = ((u64)u << 32) | (u64)(0xFFFFFFFFu - (u32)i);
      if (bin > T) { u32 p = atomicAdd(&c0, 1u); buf[p] = key; }
      else         { u32 p = atomicAdd(&c1, 1u); buf[1023 - p] = key; }
    }
  }
  __syncthreads();
  if (t == 0 && c0) base0 = atomicAdd(&cnt[img * 2 + 0], c0);
  if (t == 1 && c1) base1 = atomicAdd(&cnt[img * 2 + 1], c1);
  __syncthreads();
  u64* sb = sel + (size_t)img * 16384;
  for (u32 p = t; p < c0; p += 256) {
    u32 dpos = base0 + p;
    if (dpos < 8192u) sb[dpos] = buf[p];
  }
  for (u32 p = t; p < c1; p += 256) {
    u32 dpos = base1 + p;
    if (dpos < 8192u) sb[8192 + dpos] = buf[1023 - p];
  }
}

// K4: exact pairwise RANK. Keys unique -> rank(i) = #{j: key_j > key_i};
// sorted[rank]=key IS the descending stable sort.
__global__ void k_rank(const u64* __restrict__ sel, const u32* __restrict__ cnt,
                       const float4* __restrict__ anch, const float4* __restrict__ delt,
                       float4* __restrict__ boxes, u64* __restrict__ validw) {
  __shared__ u64 sh[1024];
  int t = threadIdx.x, img = blockIdx.y;
  u32 e0 = min(cnt[img * 2 + 0], 8192u);
  u32 e1 = min(cnt[img * 2 + 1], 8192u);
  u32 M = e0 + e1;
  if (blockIdx.x * 256u >= M) return;        // empty block, no syncthreads run
  const u64* sb = sel + (size_t)img * 16384;
  u32 ci = blockIdx.x * 256u + (u32)t;
  bool have = ci < M;
  u64 mykey = 0ull;
  if (have) mykey = (ci < e0) ? sb[ci] : sb[8192 + (ci - e0)];
  u32 rank = 0;
  for (u32 jb = 0; jb < M; jb += 1024) {
    u32 tl = min(1024u, M - jb);
    __syncthreads();
    for (u32 p = t; p < tl; p += 256) {
      u32 j = jb + p;
      sh[p] = (j < e0) ? sb[j] : sb[8192 + (j - e0)];
    }
    __syncthreads();
    if (have) {
      u32 full = tl & ~3u;
      for (u32 p = 0; p < full; p += 4) {
        rank += (sh[p]     > mykey);
        rank += (sh[p + 1] > mykey);
        rank += (sh[p + 2] > mykey);
        rank += (sh[p + 3] > mykey);
      }
      for (u32 p = full; p < tl; p++) rank += (sh[p] > mykey);
    }
  }
  if (have && rank < PRE) {
    u32 u  = (u32)(mykey >> 32);
    u32 gi = 0xFFFFFFFFu - (u32)(mykey & 0xFFFFFFFFull);
    float4 a = anch[gi];
    float4 d = delt[(size_t)img * N + gi];
    float x1, y1, x2, y2; bool valid;
    box_from(a, d, x1, y1, x2, y2, valid);
    boxes[(size_t)img * 6016 + rank] = make_float4(x1, y1, x2, y2);
    if (u != 0u)
      atomicOr(&validw[img * 96 + (rank >> 6)], 1ull << (rank & 63));
  }
}

// K5a: IoU bitmask (fast region cw<CW) + SPARSE cross-chunk edge emission.
// P(IoU>0.7) for random boxes ~1e-4 -> ~330 edges/image expected. Edges
// (src row, tgt row) with src-chunk < tgt-chunk go to a per-image list via
// LDS aggregation + ONE global atomic per block. The scan needs only these
// edges + the 40 diag blocks — the dense mask is kept solely for the rescue.
__global__ void k_mask(const float4* __restrict__ boxes, u64* __restrict__ mask,
                       u32* __restrict__ ecnt, u32* __restrict__ edges) {
  __shared__ float4 cbox[4][64];
  __shared__ float  carea[4][64];
  __shared__ u32 ebuf[512];
  __shared__ u32 ecl, ebase;
  int t = threadIdx.x;
  int rl = t & 63, g = t >> 6;
  int rb = blockIdx.x, img = blockIdx.y;     // rb in [0, CW)
  if (t == 0) ecl = 0;
  const float4* bb = boxes + (size_t)img * 6016;
  int r = rb * 64 + rl;
  float4 rx = bb[r];
  float ra = (rx.z - rx.x) * (rx.w - rx.y);
  u64* mimg = mask + (size_t)img * 94 * 6000;
  int jmax = (CW - rb + 3) >> 2;
  for (int j = 0; j < jmax; j++) {
    int cb = rb + g + 4 * j;
    bool act = cb < CW;
    __syncthreads();
    if (act) {
      float4 c = bb[cb * 64 + rl];
      cbox[g][rl] = c;
      carea[g][rl] = (c.z - c.x) * (c.w - c.y);
    }
    __syncthreads();
    if (act) {
#pragma clang fp contract(off)
      u64 bits = 0ull;
      for (int m = 0; m < 64; m++) {
        float4 cx = cbox[g][m];
        float xx1 = fmaxf(rx.x, cx.x);
        float yy1 = fmaxf(rx.y, cx.y);
        float xx2 = fminf(rx.z, cx.z);
        float yy2 = fminf(rx.w, cx.w);
        float inter = fmaxf(xx2 - xx1, 0.0f) * fmaxf(yy2 - yy1, 0.0f);
        float denom = ra + carea[g][m] - inter + 1e-9f;
        int c_j = cb * 64 + m;
        if (iou_gt(inter, denom) && c_j != r) bits |= (1ull << m);
      }
      mimg[(size_t)cb * 6000 + r] = bits;
      if (cb > rb) {                         // cross-chunk edges: src=r < tgt
        u64 eb2 = bits;
        while (eb2) {
          int m = (int)__ffsll(eb2) - 1;
          eb2 &= eb2 - 1;
          u32 p = atomicAdd(&ecl, 1u);
          if (p < 512u) ebuf[p] = (((u32)(cb * 64 + m)) << 16) | (u32)r;
        }
      }
    }
  }
  __syncthreads();
  u32 n = min(ecl, 512u);
  if (t == 0) {
    if (ecl > 512u) atomicAdd(&ecnt[img], 1000000u);   // overflow -> rescue
    ebase = n ? atomicAdd(&ecnt[img], n) : 0u;
  }
  __syncthreads();
  for (u32 p = t; p < n; p += 256) {
    u32 dp = ebase + p;
    if (dp < ECAP) edges[(size_t)img * ECAP + dp] = ebuf[p];
  }
}

// K5b: rescue — remaining triangle (cb >= max(rb,CW)). No-op when the fast
// scan succeeded for this image (okf[img]==1, the expected case).
__global__ void k_mask_rest(const float4* __restrict__ boxes, u64* __restrict__ mask,
                            const u32* __restrict__ okf) {
  int rb = blockIdx.x, img = blockIdx.y;
  if (okf[img]) return;
  __shared__ float4 cbox[4][64];
  __shared__ float  carea[4][64];
  int t = threadIdx.x;
  int rl = t & 63, g = t >> 6;
  const float4* bb = boxes + (size_t)img * 6016;
  int r = rb * 64 + rl;
  float4 rx = bb[r];
  float ra = (rx.z - rx.x) * (rx.w - rx.y);
  u64* mimg = mask + (size_t)img * 94 * 6000;
  int cb0 = rb > CW ? rb : CW;
  int jmax = (94 - cb0 + 3) >> 2;
  for (int j = 0; j < jmax; j++) {
    int cb = cb0 + g + 4 * j;
    bool act = cb < 94;
    __syncthreads();
    if (act) {
      float4 c = bb[cb * 64 + rl];
      cbox[g][rl] = c;
      carea[g][rl] = (c.z - c.x) * (c.w - c.y);
    }
    __syncthreads();
    if (act) {
#pragma clang fp contract(off)
      u64 bits = 0ull;
      for (int m = 0; m < 64; m++) {
        float4 cx = cbox[g][m];
        float xx1 = fmaxf(rx.x, cx.x);
        float yy1 = fmaxf(rx.y, cx.y);
        float xx2 = fminf(rx.z, cx.z);
        float yy2 = fminf(rx.w, cx.w);
        float inter = fmaxf(xx2 - xx1, 0.0f) * fmaxf(yy2 - yy1, 0.0f);
        float denom = ra + carea[g][m] - inter + 1e-9f;
        int c_j = cb * 64 + m;
        if (iou_gt(inter, denom) && c_j != r) bits |= (1ull << m);
      }
      if (r < PRE) mimg[(size_t)cb * 6000 + r] = bits;
    }
  }
}

// K6a: fast greedy scan — SPARSE edges + LDS diag, zero global memory on the
// resolve path. Preload: 40 diag words/lane (20KB) + edge list + validw.
// Per chunk: edge-pass (few LDS reads, kept-bit gated) + shfl-OR-tree -> su;
// scalar greedy (ffs -> readlane64(dj,js) -> andn, ~20cyc/keep) from LDS.
// Edge overflow or <KOUT keeps in CW*64 rows -> okf=0 -> exact rescue.
__global__ void __launch_bounds__(64, 1) k_scan_fast(
    const u64* __restrict__ mask, const u64* __restrict__ validw,
    const float4* __restrict__ boxes, float4* __restrict__ out,
    u32* __restrict__ okf, const u32* __restrict__ ecnt,
    const u32* __restrict__ edges) {
  __shared__ u64 dw[CW * 64];                // 20,480 B: diag blocks
  __shared__ u64 kw[CW];                     // kept bits per chunk
  __shared__ u32 eb[ECAP];                   // 16,384 B: edge list
  __shared__ unsigned short list[KOUT];      // ordered keeps
  int l = threadIdx.x;
  int img = blockIdx.x;
  const u64* mimg = mask + (size_t)img * 94 * 6000;
  // preload diag blocks (coalesced, independent) + validw (lane-owned)
  for (int c = 0; c < CW; c++) dw[c * 64 + l] = mimg[(size_t)c * 6064 + l];
  u64 vwl = validw[img * 96 + l];            // meaningful for l<CW
  u32 E = ecnt[img];
  if (E > (u32)ECAP) { if (l == 0) okf[img] = 0u; return; }
  for (u32 p = l; p < E; p += 64) eb[p] = edges[(size_t)img * ECAP + p];
  int cnt = 0; bool done = false;
  for (int c = 0; c < CW && !done; c++) {
    u64 dj = dw[c * 64 + l];                 // row (c*64+l)'s in-chunk adjacency
    // edge pass: su bits for chunk c from kept earlier rows
    u64 acc = 0ull;
    for (u32 p = l; p < E; p += 64) {
      u32 e = eb[p];
      u32 tgt = e >> 16, src = e & 0xFFFFu;
      if ((int)(tgt >> 6) == c && ((kw[src >> 6] >> (src & 63u)) & 1ull))
        acc |= 1ull << (tgt & 63u);
    }
#pragma unroll
    for (int off = 32; off >= 1; off >>= 1) acc |= __shfl_xor(acc, off);
    u64 alive = readlane64(vwl, c) & ~acc;   // uniform
    u64 keptm = 0ull;
    while (alive) {
      int js = (int)__ffsll(alive) - 1;
      keptm |= 1ull << js;
      if (l == 0 && cnt < KOUT) list[cnt] = (unsigned short)(c * 64 + js);
      cnt++;
      if (cnt >= KOUT) { done = true; break; }
      u64 row = readlane64(dj, js);
      alive &= ~row;
      alive &= ~(1ull << js);
    }
    if (l == 0) kw[c] = keptm;
  }
  if (l == 0) okf[img] = (cnt >= KOUT) ? 1u : 0u;
  __syncthreads();
  if (cnt >= KOUT) {
    for (int p = l; p < KOUT; p += 64)
      out[(size_t)img * KOUT + p] = boxes[(size_t)img * 6016 + list[p]];
  }
}

// K6b: full-depth rescue scan (94 words, rows 0..5999). No-op when fast
// scan succeeded. Identical semantics to the reference NMS.
__global__ void k_scan_full(const u64* __restrict__ mask, const u64* __restrict__ validw,
                            const float4* __restrict__ boxes, float4* __restrict__ out,
                            const u32* __restrict__ okf) {
  int img = blockIdx.x;
  if (okf[img]) return;
  __shared__ unsigned short kept[KOUT];
  int l = threadIdx.x;
  const u64* vw = validw + img * 96;
  u64 r0 = ~vw[l];
  u64 r1 = (l < MW - 64) ? ~vw[64 + l] : ~0ull;
  const u64* c0p = mask + ((size_t)img * 94 + l) * 6000;
  const u64* c1p = mask + ((size_t)img * 94 + (l < MW - 64 ? 64 + l : 0)) * 6000;

  u64 ca[16], cb[16], na[16], nb2[16];
#pragma unroll
  for (int k = 0; k < 16; k++) {
    ca[k] = c0p[k];
    cb[k] = (l < MW - 64) ? c1p[k] : 0ull;
  }
  int cnt = 0; bool done = false;
  for (int base = 0; base < PRE; base += 16) {
#pragma unroll
    for (int k = 0; k < 16; k++) {
      int rr = base + 16 + k;
      if (rr < PRE) {
        na[k]  = c0p[rr];
        nb2[k] = (l < MW - 64) ? c1p[rr] : 0ull;
      } else { na[k] = 0ull; nb2[k] = 0ull; }
    }
#pragma unroll
    for (int k = 0; k < 16; k++) {
      if (!done) {
        int i = base + k;
        int w = i >> 6;
        u64 wv = (w < 64) ? __shfl(r0, w) : __shfl(r1, w - 64);
        if (!((wv >> (i & 63)) & 1ull)) {
          if (l == 0 && cnt < KOUT) kept[cnt] = (unsigned short)i;
          cnt++;
          r0 |= (l >= w)        ? ca[k] : 0ull;
          r1 |= ((64 + l) >= w) ? cb[k] : 0ull;
          if (cnt >= KOUT) done = true;
        }
      }
    }
    if (done) break;
#pragma unroll
    for (int k = 0; k < 16; k++) { ca[k] = na[k]; cb[k] = nb2[k]; }
  }
  __syncthreads();
  for (int p = l; p < KOUT; p += 64) {
    float4 v = make_float4(0.f, 0.f, 0.f, 0.f);
    if (p < cnt) v = boxes[(size_t)img * 6016 + kept[p]];
    out[(size_t)img * KOUT + p] = v;
  }
}

extern "C" void kernel_launch(void* const* d_in, const int* in_sizes, int n_in,
                              void* d_out, int out_size, void* d_ws, size_t ws_size,
                              hipStream_t stream) {
  const float4* anch  = (const float4*)d_in[0];
  const float2* probs = (const float2*)d_in[1];
  const float4* delt  = (const float4*)d_in[2];
  float4* out = (float4*)d_out;
  char* ws = (char*)d_ws;
  (void)in_sizes; (void)n_in;

  if (ws_size < WS_NEED) {  // not enough scratch: write zeros, bail cleanly
    (void)hipMemsetAsync(d_out, 0, (size_t)out_size * sizeof(float), stream);
    return;
  }

  u64* mask    = (u64*)(ws + OFF_MASK);
  u64* sel     = (u64*)(ws + OFF_SEL);
  float4* bxs  = (float4*)(ws + OFF_BOX);
  u64* validw  = (u64*)(ws + OFF_VAL);
  u32* hist    = (u32*)(ws + OFF_HIST);
  int* Tarr    = (int*)(ws + OFF_T);
  u32* cnt     = (u32*)(ws + OFF_CNT);
  u32* okf     = (u32*)(ws + OFF_FLAG);
  u32* ecnt    = (u32*)(ws + OFF_ECNT);
  u32* edges   = (u32*)(ws + OFF_EDG);

  // zero validw + hist + Tarr + cnt + flag + ecnt every call (contiguous)
  (void)hipMemsetAsync(ws + OFF_VAL, 0, 143936, stream);

  dim3 g1(256, B);
  k_hist<<<g1, 256, 0, stream>>>(anch, probs, delt, hist, bxs);
  k_thresh<<<B, 64, 0, stream>>>(hist, Tarr);
  k_compact<<<g1, 256, 0, stream>>>(anch, probs, delt, Tarr, sel, cnt);
  dim3 g4(64, B);
  k_rank<<<g4, 256, 0, stream>>>(sel, cnt, anch, delt, bxs, validw);
  dim3 g5(CW, B);
  k_mask<<<g5, 256, 0, stream>>>(bxs, mask, ecnt, edges);
  k_scan_fast<<<B, 64, 0, stream>>>(mask, validw, bxs, out, okf, ecnt, edges);
  dim3 g5b(94, B);
  k_mask_rest<<<g5b, 256, 0, stream>>>(bxs, mask, okf);
  k_scan_full<<<B, 64, 0, stream>>>(mask, validw, bxs, out, okf);
}

// Round 14
// 401.969 us; speedup vs baseline: 1.6346x; 1.3409x over previous
//
#include <hip/hip_runtime.h>
#include <cstdint>

#define B 16
#define N 262144
#define PRE 6000
#define KOUT 1000
#define MW 94            // 64-bit mask words per row (6016 bits >= 6000)
#define CW 40            // fast-path column words: rows 0..2559
#define ECAP 4096        // per-image edge-list capacity
#define RMAX 64          // level-round cap before rescue
#define NBIN 2049
#define IMGMAX 511.0f
#define NMS_TH 0.7f

typedef unsigned int u32;
typedef unsigned long long u64;

// ---- workspace layout (bytes) ----
// mask is COLUMN-MAJOR: mask[img][cw][row], cw=0..93, row=0..5999.
#define OFF_MASK  0ull                    // 16*94*6000*8         = 72,192,000
#define OFF_SEL   72192000ull             // 16*16384*8           =  2,097,152
#define OFF_BOX   74289152ull             // 16*6016*16           =  1,540,096
#define OFF_VAL   75829248ull             // 16*96*8              =     12,288
#define OFF_HIST  75841536ull             // 16*2052*4            =    131,328
#define OFF_T     75972864ull             // 16*4                 =         64
#define OFF_CNT   75972928ull             // 16*2*4               =        128
#define OFF_FLAG  75973056ull             // 16*4                 =         64
#define OFF_ECNT  75973120ull             // 16*4                 =         64
#define OFF_EDG   75973184ull             // 16*4096*4            =    262,144
#define WS_NEED   76235328ull
// memset region each call: OFF_VAL .. OFF_ECNT+64 = 143,936 bytes

// Box decode — mirrors reference op order; contraction off so we don't fuse
// mul+add where XLA doesn't (keep/valid comparisons must match bit-for-bit).
__device__ __forceinline__ void box_from(const float4 a, const float4 d,
    float& x1, float& y1, float& x2, float& y2, bool& valid) {
#pragma clang fp contract(off)
  float w  = a.z - a.x;
  float h  = a.w - a.y;
  float cx = a.x + 0.5f * w;
  float cy = a.y + 0.5f * h;
  cx = cx + d.x * w;
  cy = cy + d.y * h;
  w = w * expf(d.z);
  h = h * expf(d.w);
  x1 = cx - 0.5f * w;
  y1 = cy - 0.5f * h;
  x2 = cx + 0.5f * w;
  y2 = cy + 0.5f * h;
  x1 = fminf(fmaxf(x1, 0.0f), IMGMAX);
  y1 = fminf(fmaxf(y1, 0.0f), IMGMAX);
  x2 = fminf(fmaxf(x2, 0.0f), IMGMAX);
  y2 = fminf(fmaxf(y2, 0.0f), IMGMAX);
  valid = ((x2 - x1) >= 16.0f) && ((y2 - y1) >= 16.0f);
}

// IoU > 0.7 decision, bit-exact vs IEEE div: fast path uses v_rcp (<=2ulp);
// only lanes with |qa-0.7| <= 1e-4 (P ~ 1e-5) take the exact-div path under
// exec mask. rcp error near 0.7 is ~2e-7 — 500x inside the guard.
__device__ __forceinline__ bool iou_gt(float inter, float denom) {
  float qa = inter * __builtin_amdgcn_rcpf(denom);
  if (__builtin_expect(fabsf(qa - NMS_TH) <= 1e-4f, 0))
    return (inter / denom) > NMS_TH;
  return qa > NMS_TH;
}

// K1: per-image score histogram, grid (256, B) — full-machine decode.
__global__ void k_hist(const float4* __restrict__ anch, const float2* __restrict__ probs,
                       const float4* __restrict__ delt, u32* __restrict__ hist,
                       float4* __restrict__ boxes) {
  __shared__ u32 sh[NBIN];
  int t = threadIdx.x;
  int img = blockIdx.y;
  if (blockIdx.x == 0 && t < 16)
    boxes[(size_t)img * 6016 + 6000 + t] = make_float4(0.f, 0.f, 0.f, 0.f);
  for (int p = t; p < NBIN; p += 256) sh[p] = 0;
  __syncthreads();
  int base = blockIdx.x * 1024;
  for (int r = 0; r < 4; r++) {
    int i = base + r * 256 + t;
    float4 a = anch[i];
    float4 d = delt[(size_t)img * N + i];
    float s = probs[(size_t)img * N + i].y;
    float x1, y1, x2, y2; bool valid;
    box_from(a, d, x1, y1, x2, y2, valid);
    int bin = valid ? (1 + min(2047, (int)(s * 2048.0f))) : 0;
    atomicAdd(&sh[bin], 1u);
  }
  __syncthreads();
  for (int p = t; p < NBIN; p += 256)
    if (sh[p]) atomicAdd(&hist[img * 2052 + p], sh[p]);
}

// K2: T = max bin b (over valid bins 1..2048) with suffix_count(b) >= PRE.
__global__ void k_thresh(const u32* __restrict__ hist, int* __restrict__ Tarr) {
  int img = blockIdx.x;
  int l = threadIdx.x;                       // 64 lanes
  const u32* hb = hist + img * 2052;
  u32 v[32];
  u32 csum = 0;
#pragma unroll
  for (int k = 0; k < 32; k++) { v[k] = hb[l * 32 + 1 + k]; csum += v[k]; }
  u32 sfx = csum;                            // suffix-inclusive over lanes >= l
  for (int off = 1; off < 64; off <<= 1) {
    u32 tv = __shfl_down(sfx, off);
    if (l + off < 64) sfx += tv;
  }
  u32 excl = sfx - csum;
  if (l == 0 && sfx < PRE) Tarr[img] = 0;    // degenerate: < PRE valid boxes
  if (excl < PRE && sfx >= PRE) {            // exactly one lane
    u32 acc = excl; int T = 0;
#pragma unroll
    for (int k = 31; k >= 0; k--) { acc += v[k]; if (acc >= PRE) { T = l * 32 + 1 + k; break; } }
    Tarr[img] = T;
  }
}

// K3: compact candidates. Block-local LDS aggregation; ONE global atomic per
// block per list. sel order nondeterministic; unique keys + exact k_rank ->
// deterministic final output.
__global__ void k_compact(const float4* __restrict__ anch, const float2* __restrict__ probs,
                          const float4* __restrict__ delt, const int* __restrict__ Tarr,
                          u64* __restrict__ sel, u32* __restrict__ cnt) {
  __shared__ u64 buf[1024];
  __shared__ u32 c0, c1, base0, base1;
  int t = threadIdx.x, img = blockIdx.y;
  if (t == 0) { c0 = 0; c1 = 0; }
  __syncthreads();
  int T = Tarr[img];
  int base = blockIdx.x * 1024;
  for (int r = 0; r < 4; r++) {
    int i = base + r * 256 + t;
    float4 a = anch[i];
    float4 d = delt[(size_t)img * N + i];
    float s = probs[(size_t)img * N + i].y;
    float x1, y1, x2, y2; bool valid;
    box_from(a, d, x1, y1, x2, y2, valid);
    int bin = valid ? (1 + min(2047, (int)(s * 2048.0f))) : 0;
    if (bin >= T) {
      u32 u = valid ? (__float_as_uint(s) | 0x80000000u) : 0u;
      u64 key = ((u64)u << 32) | (u64)(0xFFFFFFFFu - (u32)i);
      if (bin > T) { u32 p = atomicAdd(&c0, 1u); buf[p] = key; }
      else         { u32 p = atomicAdd(&c1, 1u); buf[1023 - p] = key; }
    }
  }
  __syncthreads();
  if (t == 0 && c0) base0 = atomicAdd(&cnt[img * 2 + 0], c0);
  if (t == 1 && c1) base1 = atomicAdd(&cnt[img * 2 + 1], c1);
  __syncthreads();
  u64* sb = sel + (size_t)img * 16384;
  for (u32 p = t; p < c0; p += 256) {
    u32 dpos = base0 + p;
    if (dpos < 8192u) sb[dpos] = buf[p];
  }
  for (u32 p = t; p < c1; p += 256) {
    u32 dpos = base1 + p;
    if (dpos < 8192u) sb[8192 + dpos] = buf[1023 - p];
  }
}

// K4: exact pairwise RANK. Keys unique -> rank(i) = #{j: key_j > key_i};
// sorted[rank]=key IS the descending stable sort.
__global__ void k_rank(const u64* __restrict__ sel, const u32* __restrict__ cnt,
                       const float4* __restrict__ anch, const float4* __restrict__ delt,
                       float4* __restrict__ boxes, u64* __restrict__ validw) {
  __shared__ u64 sh[1024];
  int t = threadIdx.x, img = blockIdx.y;
  u32 e0 = min(cnt[img * 2 + 0], 8192u);
  u32 e1 = min(cnt[img * 2 + 1], 8192u);
  u32 M = e0 + e1;
  if (blockIdx.x * 256u >= M) return;        // empty block, no syncthreads run
  const u64* sb = sel + (size_t)img * 16384;
  u32 ci = blockIdx.x * 256u + (u32)t;
  bool have = ci < M;
  u64 mykey = 0ull;
  if (have) mykey = (ci < e0) ? sb[ci] : sb[8192 + (ci - e0)];
  u32 rank = 0;
  for (u32 jb = 0; jb < M; jb += 1024) {
    u32 tl = min(1024u, M - jb);
    __syncthreads();
    for (u32 p = t; p < tl; p += 256) {
      u32 j = jb + p;
      sh[p] = (j < e0) ? sb[j] : sb[8192 + (j - e0)];
    }
    __syncthreads();
    if (have) {
      u32 full = tl & ~3u;
      for (u32 p = 0; p < full; p += 4) {
        rank += (sh[p]     > mykey);
        rank += (sh[p + 1] > mykey);
        rank += (sh[p + 2] > mykey);
        rank += (sh[p + 3] > mykey);
      }
      for (u32 p = full; p < tl; p++) rank += (sh[p] > mykey);
    }
  }
  if (have && rank < PRE) {
    u32 u  = (u32)(mykey >> 32);
    u32 gi = 0xFFFFFFFFu - (u32)(mykey & 0xFFFFFFFFull);
    float4 a = anch[gi];
    float4 d = delt[(size_t)img * N + gi];
    float x1, y1, x2, y2; bool valid;
    box_from(a, d, x1, y1, x2, y2, valid);
    boxes[(size_t)img * 6016 + rank] = make_float4(x1, y1, x2, y2);
    if (u != 0u)
      atomicOr(&validw[img * 96 + (rank >> 6)], 1ull << (rank & 63));
  }
}

// K5a: IoU bitmask (fast region cw<CW) + SPARSE cross-chunk edge emission.
__global__ void k_mask(const float4* __restrict__ boxes, u64* __restrict__ mask,
                       u32* __restrict__ ecnt, u32* __restrict__ edges) {
  __shared__ float4 cbox[4][64];
  __shared__ float  carea[4][64];
  __shared__ u32 ebuf[512];
  __shared__ u32 ecl, ebase;
  int t = threadIdx.x;
  int rl = t & 63, g = t >> 6;
  int rb = blockIdx.x, img = blockIdx.y;     // rb in [0, CW)
  if (t == 0) ecl = 0;
  const float4* bb = boxes + (size_t)img * 6016;
  int r = rb * 64 + rl;
  float4 rx = bb[r];
  float ra = (rx.z - rx.x) * (rx.w - rx.y);
  u64* mimg = mask + (size_t)img * 94 * 6000;
  int jmax = (CW - rb + 3) >> 2;
  for (int j = 0; j < jmax; j++) {
    int cb = rb + g + 4 * j;
    bool act = cb < CW;
    __syncthreads();
    if (act) {
      float4 c = bb[cb * 64 + rl];
      cbox[g][rl] = c;
      carea[g][rl] = (c.z - c.x) * (c.w - c.y);
    }
    __syncthreads();
    if (act) {
#pragma clang fp contract(off)
      u64 bits = 0ull;
      for (int m = 0; m < 64; m++) {
        float4 cx = cbox[g][m];
        float xx1 = fmaxf(rx.x, cx.x);
        float yy1 = fmaxf(rx.y, cx.y);
        float xx2 = fminf(rx.z, cx.z);
        float yy2 = fminf(rx.w, cx.w);
        float inter = fmaxf(xx2 - xx1, 0.0f) * fmaxf(yy2 - yy1, 0.0f);
        float denom = ra + carea[g][m] - inter + 1e-9f;
        int c_j = cb * 64 + m;
        if (iou_gt(inter, denom) && c_j != r) bits |= (1ull << m);
      }
      mimg[(size_t)cb * 6000 + r] = bits;
      if (cb > rb) {                         // cross-chunk edges: src=r < tgt
        u64 eb2 = bits;
        while (eb2) {
          int m = (int)__ffsll(eb2) - 1;
          eb2 &= eb2 - 1;
          u32 p = atomicAdd(&ecl, 1u);
          if (p < 512u) ebuf[p] = (((u32)(cb * 64 + m)) << 16) | (u32)r;
        }
      }
    }
  }
  __syncthreads();
  u32 n = min(ecl, 512u);
  if (t == 0) {
    if (ecl > 512u) atomicAdd(&ecnt[img], 1000000u);   // overflow -> rescue
    ebase = n ? atomicAdd(&ecnt[img], n) : 0u;
  }
  __syncthreads();
  for (u32 p = t; p < n; p += 256) {
    u32 dp = ebase + p;
    if (dp < ECAP) edges[(size_t)img * ECAP + dp] = ebuf[p];
  }
}

// K5b: rescue — remaining triangle (cb >= max(rb,CW)). No-op when the fast
// scan succeeded for this image (okf[img]==1, the expected case).
__global__ void k_mask_rest(const float4* __restrict__ boxes, u64* __restrict__ mask,
                            const u32* __restrict__ okf) {
  int rb = blockIdx.x, img = blockIdx.y;
  if (okf[img]) return;
  __shared__ float4 cbox[4][64];
  __shared__ float  carea[4][64];
  int t = threadIdx.x;
  int rl = t & 63, g = t >> 6;
  const float4* bb = boxes + (size_t)img * 6016;
  int r = rb * 64 + rl;
  float4 rx = bb[r];
  float ra = (rx.z - rx.x) * (rx.w - rx.y);
  u64* mimg = mask + (size_t)img * 94 * 6000;
  int cb0 = rb > CW ? rb : CW;
  int jmax = (94 - cb0 + 3) >> 2;
  for (int j = 0; j < jmax; j++) {
    int cb = cb0 + g + 4 * j;
    bool act = cb < 94;
    __syncthreads();
    if (act) {
      float4 c = bb[cb * 64 + rl];
      cbox[g][rl] = c;
      carea[g][rl] = (c.z - c.x) * (c.w - c.y);
    }
    __syncthreads();
    if (act) {
#pragma clang fp contract(off)
      u64 bits = 0ull;
      for (int m = 0; m < 64; m++) {
        float4 cx = cbox[g][m];
        float xx1 = fmaxf(rx.x, cx.x);
        float yy1 = fmaxf(rx.y, cx.y);
        float xx2 = fminf(rx.z, cx.z);
        float yy2 = fminf(rx.w, cx.w);
        float inter = fmaxf(xx2 - xx1, 0.0f) * fmaxf(yy2 - yy1, 0.0f);
        float denom = ra + carea[g][m] - inter + 1e-9f;
        int c_j = cb * 64 + m;
        if (iou_gt(inter, denom) && c_j != r) bits |= (1ull << m);
      }
      if (r < PRE) mimg[(size_t)cb * 6000 + r] = bits;
    }
  }
}

// K6a: LEVEL-SYNCHRONOUS greedy NMS (no per-keep serial loop — that chain
// cost ~460cyc x 1000 keeps = 192us across 7 prior designs; latency of a
// lone wave's dependent instructions, unfixable by data placement).
// frontier = {alive j : no alive i<j with edge(i,j)} — provably all kept
// (any earlier edge-source is already suppressed, induction). Then remove
// frontier-suppressed rows; repeat. Rounds = DAG depth (~3 for P(edge)~1e-4).
// Edges: in-chunk via LDS diag blocks; cross-chunk via sparse edge list.
// Round cap RMAX or edge overflow or <KOUT keeps -> okf=0 -> exact rescue.
__global__ void __launch_bounds__(64, 1) k_scan_fast(
    const u64* __restrict__ mask, const u64* __restrict__ validw,
    const float4* __restrict__ boxes, float4* __restrict__ out,
    u32* __restrict__ okf, const u32* __restrict__ ecnt,
    const u32* __restrict__ edges) {
  __shared__ u64 dw[CW * 64];                // 20,480 B: diag blocks
  __shared__ u64 al[CW], fw[CW], kp[CW], blkX[CW], supX[CW];
  __shared__ u32 eb[ECAP];                   // 16,384 B: edge list
  __shared__ unsigned short list[KOUT];
  int l = threadIdx.x;
  int img = blockIdx.x;
  const u64* mimg = mask + (size_t)img * 94 * 6000;
  for (int c = 0; c < CW; c++) dw[c * 64 + l] = mimg[(size_t)c * 6064 + l];
  u32 E = ecnt[img];
  if (E > (u32)ECAP) { if (l == 0) okf[img] = 0u; return; }
  for (u32 p = l; p < E; p += 64) eb[p] = edges[(size_t)img * ECAP + p];
  if (l < CW) {
    al[l] = validw[img * 96 + l];
    kp[l] = 0ull; blkX[l] = 0ull; supX[l] = 0ull;
  }
  u64 lmask = (1ull << l) - 1ull;            // earlier-in-chunk rows
  bool fail = false;
  for (int round = 0; ; round++) {
    u64 anyv = (l < CW) ? al[l] : 0ull;
#pragma unroll
    for (int off = 32; off >= 1; off >>= 1) anyv |= __shfl_xor(anyv, off);
    if (anyv == 0ull) break;                 // all rows decided
    if (round >= RMAX) { fail = true; break; }
    // cross-chunk blocked-by-alive
    for (u32 p = l; p < E; p += 64) {
      u32 e = eb[p];
      u32 tgt = e >> 16, src = e & 0xFFFFu;
      if ((al[src >> 6] >> (src & 63u)) & 1ull)
        atomicOr(&blkX[tgt >> 6], 1ull << (tgt & 63u));
    }
    // frontier per chunk (iterations independent -> pipelined)
    for (int c = 0; c < CW; c++) {
      u64 a_c = al[c];
      u64 dj = dw[c * 64 + l];
      u64 blkin = __ballot((dj & a_c & lmask) != 0ull);
      if (l == 0) fw[c] = a_c & ~blkin & ~blkX[c];
    }
    // cross-chunk suppressed-by-frontier
    for (u32 p = l; p < E; p += 64) {
      u32 e = eb[p];
      u32 tgt = e >> 16, src = e & 0xFFFFu;
      if ((fw[src >> 6] >> (src & 63u)) & 1ull)
        atomicOr(&supX[tgt >> 6], 1ull << (tgt & 63u));
    }
    // apply: keep frontier, drop suppressed, rest stay alive
    for (int c = 0; c < CW; c++) {
      u64 f_c = fw[c];
      u64 dj = dw[c * 64 + l];
      u64 supin = __ballot((dj & f_c & lmask) != 0ull);
      if (l == 0) {
        kp[c] |= f_c;
        al[c] = al[c] & ~f_c & ~supin & ~supX[c];
      }
    }
    if (l < CW) { blkX[l] = 0ull; supX[l] = 0ull; }
  }
  // prefix popcount over kept words -> ordered positions
  u64 kw_l = (!fail && l < CW) ? kp[l] : 0ull;
  u32 pc = (u32)__popcll(kw_l);
  u32 pre = pc;
  for (int off = 1; off < 64; off <<= 1) {
    u32 v2 = __shfl_up(pre, off);
    if (l >= off) pre += v2;
  }
  u32 tot = __shfl(pre, 63);
  bool ok = !fail && (tot >= (u32)KOUT);
  if (l == 0) okf[img] = ok ? 1u : 0u;
  if (!ok) return;                           // rescue path takes over
  if (l < CW) {                              // expand bits -> ordered list
    u32 b = pre - pc;
    u64 word = kw_l;
    while (word && b < (u32)KOUT) {
      int j = (int)__ffsll(word) - 1;
      word &= word - 1;
      list[b++] = (unsigned short)(l * 64 + j);
    }
  }
  for (int p = l; p < KOUT; p += 64)
    out[(size_t)img * KOUT + p] = boxes[(size_t)img * 6016 + list[p]];
}

// K6b: full-depth rescue scan (94 words, rows 0..5999). No-op when fast
// scan succeeded. Identical semantics to the reference NMS.
__global__ void k_scan_full(const u64* __restrict__ mask, const u64* __restrict__ validw,
                            const float4* __restrict__ boxes, float4* __restrict__ out,
                            const u32* __restrict__ okf) {
  int img = blockIdx.x;
  if (okf[img]) return;
  __shared__ unsigned short kept[KOUT];
  int l = threadIdx.x;
  const u64* vw = validw + img * 96;
  u64 r0 = ~vw[l];
  u64 r1 = (l < MW - 64) ? ~vw[64 + l] : ~0ull;
  const u64* c0p = mask + ((size_t)img * 94 + l) * 6000;
  const u64* c1p = mask + ((size_t)img * 94 + (l < MW - 64 ? 64 + l : 0)) * 6000;

  u64 ca[16], cb[16], na[16], nb2[16];
#pragma unroll
  for (int k = 0; k < 16; k++) {
    ca[k] = c0p[k];
    cb[k] = (l < MW - 64) ? c1p[k] : 0ull;
  }
  int cnt = 0; bool done = false;
  for (int base = 0; base < PRE; base += 16) {
#pragma unroll
    for (int k = 0; k < 16; k++) {
      int rr = base + 16 + k;
      if (rr < PRE) {
        na[k]  = c0p[rr];
        nb2[k] = (l < MW - 64) ? c1p[rr] : 0ull;
      } else { na[k] = 0ull; nb2[k] = 0ull; }
    }
#pragma unroll
    for (int k = 0; k < 16; k++) {
      if (!done) {
        int i = base + k;
        int w = i >> 6;
        u64 wv = (w < 64) ? __shfl(r0, w) : __shfl(r1, w - 64);
        if (!((wv >> (i & 63)) & 1ull)) {
          if (l == 0 && cnt < KOUT) kept[cnt] = (unsigned short)i;
          cnt++;
          r0 |= (l >= w)        ? ca[k] : 0ull;
          r1 |= ((64 + l) >= w) ? cb[k] : 0ull;
          if (cnt >= KOUT) done = true;
        }
      }
    }
    if (done) break;
#pragma unroll
    for (int k = 0; k < 16; k++) { ca[k] = na[k]; cb[k] = nb2[k]; }
  }
  __syncthreads();
  for (int p = l; p < KOUT; p += 64) {
    float4 v = make_float4(0.f, 0.f, 0.f, 0.f);
    if (p < cnt) v = boxes[(size_t)img * 6016 + kept[p]];
    out[(size_t)img * KOUT + p] = v;
  }
}

extern "C" void kernel_launch(void* const* d_in, const int* in_sizes, int n_in,
                              void* d_out, int out_size, void* d_ws, size_t ws_size,
                              hipStream_t stream) {
  const float4* anch  = (const float4*)d_in[0];
  const float2* probs = (const float2*)d_in[1];
  const float4* delt  = (const float4*)d_in[2];
  float4* out = (float4*)d_out;
  char* ws = (char*)d_ws;
  (void)in_sizes; (void)n_in;

  if (ws_size < WS_NEED) {  // not enough scratch: write zeros, bail cleanly
    (void)hipMemsetAsync(d_out, 0, (size_t)out_size * sizeof(float), stream);
    return;
  }

  u64* mask    = (u64*)(ws + OFF_MASK);
  u64* sel     = (u64*)(ws + OFF_SEL);
  float4* bxs  = (float4*)(ws + OFF_BOX);
  u64* validw  = (u64*)(ws + OFF_VAL);
  u32* hist    = (u32*)(ws + OFF_HIST);
  int* Tarr    = (int*)(ws + OFF_T);
  u32* cnt     = (u32*)(ws + OFF_CNT);
  u32* okf     = (u32*)(ws + OFF_FLAG);
  u32* ecnt    = (u32*)(ws + OFF_ECNT);
  u32* edges   = (u32*)(ws + OFF_EDG);

  // zero validw + hist + Tarr + cnt + flag + ecnt every call (contiguous)
  (void)hipMemsetAsync(ws + OFF_VAL, 0, 143936, stream);

  dim3 g1(256, B);
  k_hist<<<g1, 256, 0, stream>>>(anch, probs, delt, hist, bxs);
  k_thresh<<<B, 64, 0, stream>>>(hist, Tarr);
  k_compact<<<g1, 256, 0, stream>>>(anch, probs, delt, Tarr, sel, cnt);
  dim3 g4(64, B);
  k_rank<<<g4, 256, 0, stream>>>(sel, cnt, anch, delt, bxs, validw);
  dim3 g5(CW, B);
  k_mask<<<g5, 256, 0, stream>>>(bxs, mask, ecnt, edges);
  k_scan_fast<<<B, 64, 0, stream>>>(mask, validw, bxs, out, okf, ecnt, edges);
  dim3 g5b(94, B);
  k_mask_rest<<<g5b, 256, 0, stream>>>(bxs, mask, okf);
  k_scan_full<<<B, 64, 0, stream>>>(mask, validw, bxs, out, okf);
}

// Round 16
// 298.206 us; speedup vs baseline: 2.2034x; 1.3480x over previous
//
#include <hip/hip_runtime.h>
#include <cstdint>

#define B 16
#define N 262144
#define PRE 6000
#define KOUT 1000
#define MW 94            // 64-bit mask words per row (6016 bits >= 6000)
#define CW 40            // fast-path column words: rows 0..2559
#define ECAP 4096        // per-image edge-list capacity
#define RMAX 64          // level-round cap before rescue
#define NBIN 2049
#define IMGMAX 511.0f
#define NMS_TH 0.7f

typedef unsigned int u32;
typedef unsigned long long u64;

// ---- workspace layout (bytes) ----
// mask is COLUMN-MAJOR: mask[img][cw][row], cw=0..93, row=0..5999.
#define OFF_MASK  0ull                    // 16*94*6000*8         = 72,192,000
#define OFF_SEL   72192000ull             // 16*16384*8           =  2,097,152
#define OFF_BOX   74289152ull             // 16*6016*16           =  1,540,096
#define OFF_VAL   75829248ull             // 16*96*8              =     12,288
#define OFF_HIST  75841536ull             // 16*2052*4            =    131,328
#define OFF_CAB   75972864ull             // 16*2052*4            =    131,328
#define OFF_BCNT  76104192ull             // 16*2052*4            =    131,328
#define OFF_T     76235520ull             // 16*4                 =         64
#define OFF_M     76235584ull             // 16*4                 =         64
#define OFF_FLAG  76235648ull             // 16*4                 =         64
#define OFF_ECNT  76235712ull             // 16*4                 =         64
#define OFF_EDG   76235776ull             // 16*4096*4            =    262,144
#define WS_NEED   76497920ull
// memset region each call: OFF_VAL .. OFF_EDG = 406,528 bytes

// Box decode — mirrors reference op order; contraction off so we don't fuse
// mul+add where XLA doesn't (keep/valid comparisons must match bit-for-bit).
__device__ __forceinline__ void box_from(const float4 a, const float4 d,
    float& x1, float& y1, float& x2, float& y2, bool& valid) {
#pragma clang fp contract(off)
  float w  = a.z - a.x;
  float h  = a.w - a.y;
  float cx = a.x + 0.5f * w;
  float cy = a.y + 0.5f * h;
  cx = cx + d.x * w;
  cy = cy + d.y * h;
  w = w * expf(d.z);
  h = h * expf(d.w);
  x1 = cx - 0.5f * w;
  y1 = cy - 0.5f * h;
  x2 = cx + 0.5f * w;
  y2 = cy + 0.5f * h;
  x1 = fminf(fmaxf(x1, 0.0f), IMGMAX);
  y1 = fminf(fmaxf(y1, 0.0f), IMGMAX);
  x2 = fminf(fmaxf(x2, 0.0f), IMGMAX);
  y2 = fminf(fmaxf(y2, 0.0f), IMGMAX);
  valid = ((x2 - x1) >= 16.0f) && ((y2 - y1) >= 16.0f);
}

// IoU > 0.7 decision, bit-exact vs IEEE div: fast path uses v_rcp (<=2ulp);
// only lanes with |qa-0.7| <= 1e-4 (P ~ 1e-5) take the exact-div path under
// exec mask. rcp error near 0.7 is ~2e-7 — 500x inside the guard.
__device__ __forceinline__ bool iou_gt(float inter, float denom) {
  float qa = inter * __builtin_amdgcn_rcpf(denom);
  if (__builtin_expect(fabsf(qa - NMS_TH) <= 1e-4f, 0))
    return (inter / denom) > NMS_TH;
  return qa > NMS_TH;
}

__device__ __forceinline__ int bin_of(u32 u) {
  if (u == 0u) return 0;
  float s = __uint_as_float(u & 0x7FFFFFFFu);
  return 1 + min(2047, (int)(s * 2048.0f));
}

// K1: per-image score histogram, grid (256, B) — full-machine decode.
__global__ void k_hist(const float4* __restrict__ anch, const float2* __restrict__ probs,
                       const float4* __restrict__ delt, u32* __restrict__ hist,
                       float4* __restrict__ boxes) {
  __shared__ u32 sh[NBIN];
  int t = threadIdx.x;
  int img = blockIdx.y;
  if (blockIdx.x == 0 && t < 16)
    boxes[(size_t)img * 6016 + 6000 + t] = make_float4(0.f, 0.f, 0.f, 0.f);
  for (int p = t; p < NBIN; p += 256) sh[p] = 0;
  __syncthreads();
  int base = blockIdx.x * 1024;
  for (int r = 0; r < 4; r++) {
    int i = base + r * 256 + t;
    float4 a = anch[i];
    float4 d = delt[(size_t)img * N + i];
    float s = probs[(size_t)img * N + i].y;
    float x1, y1, x2, y2; bool valid;
    box_from(a, d, x1, y1, x2, y2, valid);
    int bin = valid ? (1 + min(2047, (int)(s * 2048.0f))) : 0;
    atomicAdd(&sh[bin], 1u);
  }
  __syncthreads();
  for (int p = t; p < NBIN; p += 256)
    if (sh[p]) atomicAdd(&hist[img * 2052 + p], sh[p]);
}

// K2: T = max bin b with suffix_count(b) >= PRE; ALSO writes the per-bin
// count-above table cab[b] = #keys in bins > b (the sort's coarse level)
// and M = candidate count. rank(K) = cab[bin(K)] + within-bin rank.
__global__ void k_thresh(const u32* __restrict__ hist, int* __restrict__ Tarr,
                         u32* __restrict__ cab, u32* __restrict__ Marr) {
  int img = blockIdx.x;
  int l = threadIdx.x;                       // 64 lanes
  const u32* hb = hist + img * 2052;
  u32 v[32];
  u32 csum = 0;
#pragma unroll
  for (int k = 0; k < 32; k++) { v[k] = hb[l * 32 + 1 + k]; csum += v[k]; }
  u32 sfx = csum;                            // suffix-inclusive over lanes >= l
  for (int off = 1; off < 64; off <<= 1) {
    u32 tv = __shfl_down(sfx, off);
    if (l + off < 64) sfx += tv;
  }
  u32 excl = sfx - csum;                     // sum over lanes > l
  // per-bin count-above: lane-local suffix + excl
  u32 ss = 0;                                // suffix sum over k' > k
  u32 outv[32];
#pragma unroll
  for (int k = 31; k >= 0; k--) { outv[k] = ss + excl; ss += v[k]; }
  u32* cb = cab + img * 2052;
#pragma unroll
  for (int k = 0; k < 32; k++) cb[l * 32 + 1 + k] = outv[k];
  u32 total = __shfl(sfx, 0);                // total valid keys
  if (l == 0) cb[0] = total;
  if (l == 0 && total < PRE) { Tarr[img] = 0; Marr[img] = 16384u; }
  if (excl < PRE && sfx >= PRE) {            // exactly one lane (if total>=PRE)
    u32 acc = excl; int T = 0; u32 Mv = 0;
#pragma unroll
    for (int k = 31; k >= 0; k--) {
      acc += v[k];
      if (acc >= PRE) { T = l * 32 + 1 + k; Mv = acc; break; }
    }
    Tarr[img] = T; Marr[img] = Mv;
  }
}

// K3: compact candidates directly into BIN SEGMENTS of sel:
// dst = cab[bin] + atomicAdd(bincnt[bin]). Bin-level atomics: ~128-deep
// chains spread over ~2048 addresses (R3's disaster was 6000-deep over 2).
// Segment order is arbitrary; k_rank's within-bin ranking makes the final
// placement exact and deterministic (keys unique).
__global__ void k_compact(const float4* __restrict__ anch, const float2* __restrict__ probs,
                          const float4* __restrict__ delt, const int* __restrict__ Tarr,
                          const u32* __restrict__ cab, u32* __restrict__ bincnt,
                          u64* __restrict__ sel) {
  int t = threadIdx.x, img = blockIdx.y;
  int T = Tarr[img];
  const u32* cb = cab + img * 2052;
  int base = blockIdx.x * 1024;
  for (int r = 0; r < 4; r++) {
    int i = base + r * 256 + t;
    float4 a = anch[i];
    float4 d = delt[(size_t)img * N + i];
    float s = probs[(size_t)img * N + i].y;
    float x1, y1, x2, y2; bool valid;
    box_from(a, d, x1, y1, x2, y2, valid);
    int bin = valid ? (1 + min(2047, (int)(s * 2048.0f))) : 0;
    if (bin >= T) {
      u32 u = valid ? (__float_as_uint(s) | 0x80000000u) : 0u;
      u64 key = ((u64)u << 32) | (u64)(0xFFFFFFFFu - (u32)i);
      u32 p = atomicAdd(&bincnt[img * 2052 + bin], 1u);
      u32 dst = cb[bin] + p;
      if (dst < 16384u) sel[(size_t)img * 16384 + dst] = key;
    }
  }
}

// K4: within-bin exact rank. Thread's candidate compares ONLY against its
// own bin segment (~128 keys, L2-broadcast reads) — 47x less work than the
// old all-pairs M^2. rank = cab[bin] + within; rank < PRE -> decode box,
// scatter, set validw bit. Ranks are a dense exact permutation.
__global__ void k_rank(const u64* __restrict__ sel, const u32* __restrict__ cab,
                       const u32* __restrict__ hist, const u32* __restrict__ Marr,
                       const float4* __restrict__ anch, const float4* __restrict__ delt,
                       float4* __restrict__ boxes, u64* __restrict__ validw) {
  int t = threadIdx.x, img = blockIdx.y;
  u32 M = min(Marr[img], 16384u);
  u32 ci = blockIdx.x * 256u + (u32)t;
  if (ci >= M) return;
  const u64* sb = sel + (size_t)img * 16384;
  u64 key = sb[ci];
  u32 u = (u32)(key >> 32);
  int bin = bin_of(u);
  const u32* cb = cab + img * 2052;
  u32 segs = cb[bin];
  u32 sege;
  if (bin > 0) sege = cb[bin - 1];
  else         sege = min(16384u, segs + hist[img * 2052 + 0]);
  if (sege > 16384u) sege = 16384u;
  u32 within = 0;
  u32 j = segs;
  for (; j + 4 <= sege; j += 4) {
    within += (sb[j]     > key);
    within += (sb[j + 1] > key);
    within += (sb[j + 2] > key);
    within += (sb[j + 3] > key);
  }
  for (; j < sege; j++) within += (sb[j] > key);
  u32 rank = segs + within;
  if (rank < PRE) {
    u32 gi = 0xFFFFFFFFu - (u32)(key & 0xFFFFFFFFull);
    float4 a = anch[gi];
    float4 d = delt[(size_t)img * N + gi];
    float x1, y1, x2, y2; bool valid;
    box_from(a, d, x1, y1, x2, y2, valid);
    boxes[(size_t)img * 6016 + rank] = make_float4(x1, y1, x2, y2);
    if (u != 0u)
      atomicOr(&validw[img * 96 + (rank >> 6)], 1ull << (rank & 63));
  }
}

// K5a: IoU bitmask (fast region cw<CW) + SPARSE cross-chunk edge emission.
__global__ void k_mask(const float4* __restrict__ boxes, u64* __restrict__ mask,
                       u32* __restrict__ ecnt, u32* __restrict__ edges) {
  __shared__ float4 cbox[4][64];
  __shared__ float  carea[4][64];
  __shared__ u32 ebuf[512];
  __shared__ u32 ecl, ebase;
  int t = threadIdx.x;
  int rl = t & 63, g = t >> 6;
  int rb = blockIdx.x, img = blockIdx.y;     // rb in [0, CW)
  if (t == 0) ecl = 0;
  const float4* bb = boxes + (size_t)img * 6016;
  int r = rb * 64 + rl;
  float4 rx = bb[r];
  float ra = (rx.z - rx.x) * (rx.w - rx.y);
  u64* mimg = mask + (size_t)img * 94 * 6000;
  int jmax = (CW - rb + 3) >> 2;
  for (int j = 0; j < jmax; j++) {
    int cb = rb + g + 4 * j;
    bool act = cb < CW;
    __syncthreads();
    if (act) {
      float4 c = bb[cb * 64 + rl];
      cbox[g][rl] = c;
      carea[g][rl] = (c.z - c.x) * (c.w - c.y);
    }
    __syncthreads();
    if (act) {
#pragma clang fp contract(off)
      u64 bits = 0ull;
      for (int m = 0; m < 64; m++) {
        float4 cx = cbox[g][m];
        float xx1 = fmaxf(rx.x, cx.x);
        float yy1 = fmaxf(rx.y, cx.y);
        float xx2 = fminf(rx.z, cx.z);
        float yy2 = fminf(rx.w, cx.w);
        float inter = fmaxf(xx2 - xx1, 0.0f) * fmaxf(yy2 - yy1, 0.0f);
        float denom = ra + carea[g][m] - inter + 1e-9f;
        int c_j = cb * 64 + m;
        if (iou_gt(inter, denom) && c_j != r) bits |= (1ull << m);
      }
      mimg[(size_t)cb * 6000 + r] = bits;
      if (cb > rb) {                         // cross-chunk edges: src=r < tgt
        u64 eb2 = bits;
        while (eb2) {
          int m = (int)__ffsll(eb2) - 1;
          eb2 &= eb2 - 1;
          u32 p = atomicAdd(&ecl, 1u);
          if (p < 512u) ebuf[p] = (((u32)(cb * 64 + m)) << 16) | (u32)r;
        }
      }
    }
  }
  __syncthreads();
  u32 n = min(ecl, 512u);
  if (t == 0) {
    if (ecl > 512u) atomicAdd(&ecnt[img], 1000000u);   // overflow -> rescue
    ebase = n ? atomicAdd(&ecnt[img], n) : 0u;
  }
  __syncthreads();
  for (u32 p = t; p < n; p += 256) {
    u32 dp = ebase + p;
    if (dp < ECAP) edges[(size_t)img * ECAP + dp] = ebuf[p];
  }
}

// K5b: rescue — remaining triangle (cb >= max(rb,CW)). No-op when the fast
// scan succeeded for this image (okf[img]==1, the expected case).
__global__ void k_mask_rest(const float4* __restrict__ boxes, u64* __restrict__ mask,
                            const u32* __restrict__ okf) {
  int rb = blockIdx.x, img = blockIdx.y;
  if (okf[img]) return;
  __shared__ float4 cbox[4][64];
  __shared__ float  carea[4][64];
  int t = threadIdx.x;
  int rl = t & 63, g = t >> 6;
  const float4* bb = boxes + (size_t)img * 6016;
  int r = rb * 64 + rl;
  float4 rx = bb[r];
  float ra = (rx.z - rx.x) * (rx.w - rx.y);
  u64* mimg = mask + (size_t)img * 94 * 6000;
  int cb0 = rb > CW ? rb : CW;
  int jmax = (94 - cb0 + 3) >> 2;
  for (int j = 0; j < jmax; j++) {
    int cb = cb0 + g + 4 * j;
    bool act = cb < 94;
    __syncthreads();
    if (act) {
      float4 c = bb[cb * 64 + rl];
      cbox[g][rl] = c;
      carea[g][rl] = (c.z - c.x) * (c.w - c.y);
    }
    __syncthreads();
    if (act) {
#pragma clang fp contract(off)
      u64 bits = 0ull;
      for (int m = 0; m < 64; m++) {
        float4 cx = cbox[g][m];
        float xx1 = fmaxf(rx.x, cx.x);
        float yy1 = fmaxf(rx.y, cx.y);
        float xx2 = fminf(rx.z, cx.z);
        float yy2 = fminf(rx.w, cx.w);
        float inter = fmaxf(xx2 - xx1, 0.0f) * fmaxf(yy2 - yy1, 0.0f);
        float denom = ra + carea[g][m] - inter + 1e-9f;
        int c_j = cb * 64 + m;
        if (iou_gt(inter, denom) && c_j != r) bits |= (1ull << m);
      }
      if (r < PRE) mimg[(size_t)cb * 6000 + r] = bits;
    }
  }
}

// K6a: LEVEL-SYNCHRONOUS greedy NMS (R14, verified): frontier rounds retire
// whole DAG levels; depth ~3 for P(edge)~1e-4. Exact by induction.
__global__ void __launch_bounds__(64, 1) k_scan_fast(
    const u64* __restrict__ mask, const u64* __restrict__ validw,
    const float4* __restrict__ boxes, float4* __restrict__ out,
    u32* __restrict__ okf, const u32* __restrict__ ecnt,
    const u32* __restrict__ edges) {
  __shared__ u64 dw[CW * 64];                // 20,480 B: diag blocks
  __shared__ u64 al[CW], fw[CW], kp[CW], blkX[CW], supX[CW];
  __shared__ u32 eb[ECAP];                   // 16,384 B: edge list
  __shared__ unsigned short list[KOUT];
  int l = threadIdx.x;
  int img = blockIdx.x;
  const u64* mimg = mask + (size_t)img * 94 * 6000;
  for (int c = 0; c < CW; c++) dw[c * 64 + l] = mimg[(size_t)c * 6064 + l];
  u32 E = ecnt[img];
  if (E > (u32)ECAP) { if (l == 0) okf[img] = 0u; return; }
  for (u32 p = l; p < E; p += 64) eb[p] = edges[(size_t)img * ECAP + p];
  if (l < CW) {
    al[l] = validw[img * 96 + l];
    kp[l] = 0ull; blkX[l] = 0ull; supX[l] = 0ull;
  }
  u64 lmask = (1ull << l) - 1ull;            // earlier-in-chunk rows
  bool fail = false;
  for (int round = 0; ; round++) {
    u64 anyv = (l < CW) ? al[l] : 0ull;
#pragma unroll
    for (int off = 32; off >= 1; off >>= 1) anyv |= __shfl_xor(anyv, off);
    if (anyv == 0ull) break;                 // all rows decided
    if (round >= RMAX) { fail = true; break; }
    // cross-chunk blocked-by-alive
    for (u32 p = l; p < E; p += 64) {
      u32 e = eb[p];
      u32 tgt = e >> 16, src = e & 0xFFFFu;
      if ((al[src >> 6] >> (src & 63u)) & 1ull)
        atomicOr(&blkX[tgt >> 6], 1ull << (tgt & 63u));
    }
    // frontier per chunk (iterations independent -> pipelined)
    for (int c = 0; c < CW; c++) {
      u64 a_c = al[c];
      u64 dj = dw[c * 64 + l];
      u64 blkin = __ballot((dj & a_c & lmask) != 0ull);
      if (l == 0) fw[c] = a_c & ~blkin & ~blkX[c];
    }
    // cross-chunk suppressed-by-frontier
    for (u32 p = l; p < E; p += 64) {
      u32 e = eb[p];
      u32 tgt = e >> 16, src = e & 0xFFFFu;
      if ((fw[src >> 6] >> (src & 63u)) & 1ull)
        atomicOr(&supX[tgt >> 6], 1ull << (tgt & 63u));
    }
    // apply: keep frontier, drop suppressed, rest stay alive
    for (int c = 0; c < CW; c++) {
      u64 f_c = fw[c];
      u64 dj = dw[c * 64 + l];
      u64 supin = __ballot((dj & f_c & lmask) != 0ull);
      if (l == 0) {
        kp[c] |= f_c;
        al[c] = al[c] & ~f_c & ~supin & ~supX[c];
      }
    }
    if (l < CW) { blkX[l] = 0ull; supX[l] = 0ull; }
  }
  // prefix popcount over kept words -> ordered positions
  u64 kw_l = (!fail && l < CW) ? kp[l] : 0ull;
  u32 pc = (u32)__popcll(kw_l);
  u32 pre = pc;
  for (int off = 1; off < 64; off <<= 1) {
    u32 v2 = __shfl_up(pre, off);
    if (l >= off) pre += v2;
  }
  u32 tot = __shfl(pre, 63);
  bool ok = !fail && (tot >= (u32)KOUT);
  if (l == 0) okf[img] = ok ? 1u : 0u;
  if (!ok) return;                           // rescue path takes over
  if (l < CW) {                              // expand bits -> ordered list
    u32 b = pre - pc;
    u64 word = kw_l;
    while (word && b < (u32)KOUT) {
      int j = (int)__ffsll(word) - 1;
      word &= word - 1;
      list[b++] = (unsigned short)(l * 64 + j);
    }
  }
  for (int p = l; p < KOUT; p += 64)
    out[(size_t)img * KOUT + p] = boxes[(size_t)img * 6016 + list[p]];
}

// K6b: full-depth rescue scan (94 words, rows 0..5999). No-op when fast
// scan succeeded. Identical semantics to the reference NMS.
__global__ void k_scan_full(const u64* __restrict__ mask, const u64* __restrict__ validw,
                            const float4* __restrict__ boxes, float4* __restrict__ out,
                            const u32* __restrict__ okf) {
  int img = blockIdx.x;
  if (okf[img]) return;
  __shared__ unsigned short kept[KOUT];
  int l = threadIdx.x;
  const u64* vw = validw + img * 96;
  u64 r0 = ~vw[l];
  u64 r1 = (l < MW - 64) ? ~vw[64 + l] : ~0ull;
  const u64* c0p = mask + ((size_t)img * 94 + l) * 6000;
  const u64* c1p = mask + ((size_t)img * 94 + (l < MW - 64 ? 64 + l : 0)) * 6000;

  u64 ca[16], cb[16], na[16], nb2[16];
#pragma unroll
  for (int k = 0; k < 16; k++) {
    ca[k] = c0p[k];
    cb[k] = (l < MW - 64) ? c1p[k] : 0ull;
  }
  int cnt = 0; bool done = false;
  for (int base = 0; base < PRE; base += 16) {
#pragma unroll
    for (int k = 0; k < 16; k++) {
      int rr = base + 16 + k;
      if (rr < PRE) {
        na[k]  = c0p[rr];
        nb2[k] = (l < MW - 64) ? c1p[rr] : 0ull;
      } else { na[k] = 0ull; nb2[k] = 0ull; }
    }
#pragma unroll
    for (int k = 0; k < 16; k++) {
      if (!done) {
        int i = base + k;
        int w = i >> 6;
        u64 wv = (w < 64) ? __shfl(r0, w) : __shfl(r1, w - 64);
        if (!((wv >> (i & 63)) & 1ull)) {
          if (l == 0 && cnt < KOUT) kept[cnt] = (unsigned short)i;
          cnt++;
          r0 |= (l >= w)        ? ca[k] : 0ull;
          r1 |= ((64 + l) >= w) ? cb[k] : 0ull;
          if (cnt >= KOUT) done = true;
        }
      }
    }
    if (done) break;
#pragma unroll
    for (int k = 0; k < 16; k++) { ca[k] = na[k]; cb[k] = nb2[k]; }
  }
  __syncthreads();
  for (int p = l; p < KOUT; p += 64) {
    float4 v = make_float4(0.f, 0.f, 0.f, 0.f);
    if (p < cnt) v = boxes[(size_t)img * 6016 + kept[p]];
    out[(size_t)img * KOUT + p] = v;
  }
}

extern "C" void kernel_launch(void* const* d_in, const int* in_sizes, int n_in,
                              void* d_out, int out_size, void* d_ws, size_t ws_size,
                              hipStream_t stream) {
  const float4* anch  = (const float4*)d_in[0];
  const float2* probs = (const float2*)d_in[1];
  const float4* delt  = (const float4*)d_in[2];
  float4* out = (float4*)d_out;
  char* ws = (char*)d_ws;
  (void)in_sizes; (void)n_in;

  if (ws_size < WS_NEED) {  // not enough scratch: write zeros, bail cleanly
    (void)hipMemsetAsync(d_out, 0, (size_t)out_size * sizeof(float), stream);
    return;
  }

  u64* mask    = (u64*)(ws + OFF_MASK);
  u64* sel     = (u64*)(ws + OFF_SEL);
  float4* bxs  = (float4*)(ws + OFF_BOX);
  u64* validw  = (u64*)(ws + OFF_VAL);
  u32* hist    = (u32*)(ws + OFF_HIST);
  u32* cab     = (u32*)(ws + OFF_CAB);
  u32* bincnt  = (u32*)(ws + OFF_BCNT);
  int* Tarr    = (int*)(ws + OFF_T);
  u32* Marr    = (u32*)(ws + OFF_M);
  u32* okf     = (u32*)(ws + OFF_FLAG);
  u32* ecnt    = (u32*)(ws + OFF_ECNT);
  u32* edges   = (u32*)(ws + OFF_EDG);

  // zero validw+hist+cab+bincnt+T+M+flag+ecnt every call (contiguous)
  (void)hipMemsetAsync(ws + OFF_VAL, 0, 406528, stream);

  dim3 g1(256, B);
  k_hist<<<g1, 256, 0, stream>>>(anch, probs, delt, hist, bxs);
  k_thresh<<<B, 64, 0, stream>>>(hist, Tarr, cab, Marr);
  k_compact<<<g1, 256, 0, stream>>>(anch, probs, delt, Tarr, cab, bincnt, sel);
  dim3 g4(64, B);
  k_rank<<<g4, 256, 0, stream>>>(sel, cab, hist, Marr, anch, delt, bxs, validw);
  dim3 g5(CW, B);
  k_mask<<<g5, 256, 0, stream>>>(bxs, mask, ecnt, edges);
  k_scan_fast<<<B, 64, 0, stream>>>(mask, validw, bxs, out, okf, ecnt, edges);
  dim3 g5b(94, B);
  k_mask_rest<<<g5b, 256, 0, stream>>>(bxs, mask, okf);
  k_scan_full<<<B, 64, 0, stream>>>(mask, validw, bxs, out, okf);
}

// Round 17
// 291.466 us; speedup vs baseline: 2.2543x; 1.0231x over previous
//
#include <hip/hip_runtime.h>
#include <cstdint>

#define B 16
#define N 262144
#define PRE 6000
#define KOUT 1000
#define MW 94            // 64-bit mask words per row (6016 bits >= 6000)
#define CW 40            // fast-path column words: rows 0..2559
#define ECAP 4096        // per-image edge-list capacity
#define RMAX 64          // level-round cap before rescue
#define NBIN 2049
#define IMGMAX 511.0f
#define NMS_TH 0.7f

typedef unsigned int u32;
typedef unsigned long long u64;

// ---- workspace layout (bytes) ----
// mask is COLUMN-MAJOR: mask[img][cw][row], cw=0..93, row=0..5999.
#define OFF_MASK  0ull                    // 16*94*6000*8         = 72,192,000
#define OFF_SEL   72192000ull             // 16*16384*8           =  2,097,152
#define OFF_BOX   74289152ull             // 16*6016*16           =  1,540,096
#define OFF_VAL   75829248ull             // 16*96*8              =     12,288
#define OFF_HIST  75841536ull             // 16*2052*4            =    131,328
#define OFF_CAB   75972864ull             // 16*2052*4            =    131,328
#define OFF_BCNT  76104192ull             // 16*2052*4            =    131,328
#define OFF_T     76235520ull             // 16*4                 =         64
#define OFF_M     76235584ull             // 16*4                 =         64
#define OFF_FLAG  76235648ull             // 16*4                 =         64
#define OFF_ECNT  76235712ull             // 16*4                 =         64
#define OFF_EDG   76235776ull             // 16*4096*4            =    262,144
#define WS_NEED   76497920ull
// memset region each call: OFF_VAL .. OFF_EDG = 406,528 bytes

// Box decode — mirrors reference op order; contraction off so we don't fuse
// mul+add where XLA doesn't (keep/valid comparisons must match bit-for-bit).
__device__ __forceinline__ void box_from(const float4 a, const float4 d,
    float& x1, float& y1, float& x2, float& y2, bool& valid) {
#pragma clang fp contract(off)
  float w  = a.z - a.x;
  float h  = a.w - a.y;
  float cx = a.x + 0.5f * w;
  float cy = a.y + 0.5f * h;
  cx = cx + d.x * w;
  cy = cy + d.y * h;
  w = w * expf(d.z);
  h = h * expf(d.w);
  x1 = cx - 0.5f * w;
  y1 = cy - 0.5f * h;
  x2 = cx + 0.5f * w;
  y2 = cy + 0.5f * h;
  x1 = fminf(fmaxf(x1, 0.0f), IMGMAX);
  y1 = fminf(fmaxf(y1, 0.0f), IMGMAX);
  x2 = fminf(fmaxf(x2, 0.0f), IMGMAX);
  y2 = fminf(fmaxf(y2, 0.0f), IMGMAX);
  valid = ((x2 - x1) >= 16.0f) && ((y2 - y1) >= 16.0f);
}

// IoU > 0.7 decision, bit-exact vs IEEE div: fast path uses v_rcp (<=2ulp);
// only lanes with |qa-0.7| <= 1e-4 (P ~ 1e-5) take the exact-div path under
// exec mask. rcp error near 0.7 is ~2e-7 — 500x inside the guard.
__device__ __forceinline__ bool iou_gt(float inter, float denom) {
  float qa = inter * __builtin_amdgcn_rcpf(denom);
  if (__builtin_expect(fabsf(qa - NMS_TH) <= 1e-4f, 0))
    return (inter / denom) > NMS_TH;
  return qa > NMS_TH;
}

__device__ __forceinline__ int bin_of(u32 u) {
  if (u == 0u) return 0;
  float s = __uint_as_float(u & 0x7FFFFFFFu);
  return 1 + min(2047, (int)(s * 2048.0f));
}

// K1: per-image score histogram, grid (256, B) — full-machine decode.
__global__ void k_hist(const float4* __restrict__ anch, const float2* __restrict__ probs,
                       const float4* __restrict__ delt, u32* __restrict__ hist,
                       float4* __restrict__ boxes) {
  __shared__ u32 sh[NBIN];
  int t = threadIdx.x;
  int img = blockIdx.y;
  if (blockIdx.x == 0 && t < 16)
    boxes[(size_t)img * 6016 + 6000 + t] = make_float4(0.f, 0.f, 0.f, 0.f);
  for (int p = t; p < NBIN; p += 256) sh[p] = 0;
  __syncthreads();
  int base = blockIdx.x * 1024;
  for (int r = 0; r < 4; r++) {
    int i = base + r * 256 + t;
    float4 a = anch[i];
    float4 d = delt[(size_t)img * N + i];
    float s = probs[(size_t)img * N + i].y;
    float x1, y1, x2, y2; bool valid;
    box_from(a, d, x1, y1, x2, y2, valid);
    int bin = valid ? (1 + min(2047, (int)(s * 2048.0f))) : 0;
    atomicAdd(&sh[bin], 1u);
  }
  __syncthreads();
  for (int p = t; p < NBIN; p += 256)
    if (sh[p]) atomicAdd(&hist[img * 2052 + p], sh[p]);
}

// K2: T = max bin b with suffix_count(b) >= PRE; ALSO writes the per-bin
// count-above table cab[b] = #keys in bins > b (the sort's coarse level)
// and M = candidate count. rank(K) = cab[bin(K)] + within-bin rank.
__global__ void k_thresh(const u32* __restrict__ hist, int* __restrict__ Tarr,
                         u32* __restrict__ cab, u32* __restrict__ Marr) {
  int img = blockIdx.x;
  int l = threadIdx.x;                       // 64 lanes
  const u32* hb = hist + img * 2052;
  u32 v[32];
  u32 csum = 0;
#pragma unroll
  for (int k = 0; k < 32; k++) { v[k] = hb[l * 32 + 1 + k]; csum += v[k]; }
  u32 sfx = csum;                            // suffix-inclusive over lanes >= l
  for (int off = 1; off < 64; off <<= 1) {
    u32 tv = __shfl_down(sfx, off);
    if (l + off < 64) sfx += tv;
  }
  u32 excl = sfx - csum;                     // sum over lanes > l
  // per-bin count-above: lane-local suffix + excl
  u32 ss = 0;                                // suffix sum over k' > k
  u32 outv[32];
#pragma unroll
  for (int k = 31; k >= 0; k--) { outv[k] = ss + excl; ss += v[k]; }
  u32* cb = cab + img * 2052;
#pragma unroll
  for (int k = 0; k < 32; k++) cb[l * 32 + 1 + k] = outv[k];
  u32 total = __shfl(sfx, 0);                // total valid keys
  if (l == 0) cb[0] = total;
  if (l == 0 && total < PRE) { Tarr[img] = 0; Marr[img] = 16384u; }
  if (excl < PRE && sfx >= PRE) {            // exactly one lane (if total>=PRE)
    u32 acc = excl; int T = 0; u32 Mv = 0;
#pragma unroll
    for (int k = 31; k >= 0; k--) {
      acc += v[k];
      if (acc >= PRE) { T = l * 32 + 1 + k; Mv = acc; break; }
    }
    Tarr[img] = T; Marr[img] = Mv;
  }
}

// K3: compact candidates directly into BIN SEGMENTS of sel:
// dst = cab[bin] + atomicAdd(bincnt[bin]). Bin-level atomics: ~128-deep
// chains spread over ~2048 addresses. Segment order arbitrary; k_rank's
// within-bin ranking makes the final placement exact and deterministic.
__global__ void k_compact(const float4* __restrict__ anch, const float2* __restrict__ probs,
                          const float4* __restrict__ delt, const int* __restrict__ Tarr,
                          const u32* __restrict__ cab, u32* __restrict__ bincnt,
                          u64* __restrict__ sel) {
  int t = threadIdx.x, img = blockIdx.y;
  int T = Tarr[img];
  const u32* cb = cab + img * 2052;
  int base = blockIdx.x * 1024;
  for (int r = 0; r < 4; r++) {
    int i = base + r * 256 + t;
    float4 a = anch[i];
    float4 d = delt[(size_t)img * N + i];
    float s = probs[(size_t)img * N + i].y;
    float x1, y1, x2, y2; bool valid;
    box_from(a, d, x1, y1, x2, y2, valid);
    int bin = valid ? (1 + min(2047, (int)(s * 2048.0f))) : 0;
    if (bin >= T) {
      u32 u = valid ? (__float_as_uint(s) | 0x80000000u) : 0u;
      u64 key = ((u64)u << 32) | (u64)(0xFFFFFFFFu - (u32)i);
      u32 p = atomicAdd(&bincnt[img * 2052 + bin], 1u);
      u32 dst = cb[bin] + p;
      if (dst < 16384u) sel[(size_t)img * 16384 + dst] = key;
    }
  }
}

// K4: within-bin exact rank. Thread's candidate compares ONLY against its
// own bin segment (~128 keys, L2-broadcast reads). rank = cab[bin] + within;
// rank < PRE -> decode box, scatter, set validw bit. Exact dense permutation.
__global__ void k_rank(const u64* __restrict__ sel, const u32* __restrict__ cab,
                       const u32* __restrict__ hist, const u32* __restrict__ Marr,
                       const float4* __restrict__ anch, const float4* __restrict__ delt,
                       float4* __restrict__ boxes, u64* __restrict__ validw) {
  int t = threadIdx.x, img = blockIdx.y;
  u32 M = min(Marr[img], 16384u);
  u32 ci = blockIdx.x * 256u + (u32)t;
  if (ci >= M) return;
  const u64* sb = sel + (size_t)img * 16384;
  u64 key = sb[ci];
  u32 u = (u32)(key >> 32);
  int bin = bin_of(u);
  const u32* cb = cab + img * 2052;
  u32 segs = cb[bin];
  u32 sege;
  if (bin > 0) sege = cb[bin - 1];
  else         sege = min(16384u, segs + hist[img * 2052 + 0]);
  if (sege > 16384u) sege = 16384u;
  u32 within = 0;
  u32 j = segs;
  for (; j + 4 <= sege; j += 4) {
    within += (sb[j]     > key);
    within += (sb[j + 1] > key);
    within += (sb[j + 2] > key);
    within += (sb[j + 3] > key);
  }
  for (; j < sege; j++) within += (sb[j] > key);
  u32 rank = segs + within;
  if (rank < PRE) {
    u32 gi = 0xFFFFFFFFu - (u32)(key & 0xFFFFFFFFull);
    float4 a = anch[gi];
    float4 d = delt[(size_t)img * N + gi];
    float x1, y1, x2, y2; bool valid;
    box_from(a, d, x1, y1, x2, y2, valid);
    boxes[(size_t)img * 6016 + rank] = make_float4(x1, y1, x2, y2);
    if (u != 0u)
      atomicOr(&validw[img * 96 + (rank >> 6)], 1ull << (rank & 63));
  }
}

// K5a: IoU bitmask (fast region) — FLATTENED: one 64x64 tile per 1-wave
// block, grid (CW*CW, B), cb<rb blocks exit. Old version: 40 blocks/img
// with a triangular barrier loop -> 14.8% occupancy, 35% VALUBusy, 101us
// for ~11us of VALU work. Now ~13k independent waves, no loops/imbalance.
__global__ void __launch_bounds__(64) k_mask(
    const float4* __restrict__ boxes, u64* __restrict__ mask,
    u32* __restrict__ ecnt, u32* __restrict__ edges) {
  int rb = blockIdx.x / CW, cb = blockIdx.x % CW;
  if (cb < rb) return;
  int img = blockIdx.y;
  __shared__ float4 cbox[64];
  __shared__ float  carea[64];
  __shared__ u32 ebuf[256];
  __shared__ u32 ecl, ebase;
  int l = threadIdx.x;
  if (l == 0) ecl = 0;
  const float4* bb = boxes + (size_t)img * 6016;
  int r = rb * 64 + l;
  float4 rx = bb[r];
  float ra = (rx.z - rx.x) * (rx.w - rx.y);
  float4 c = bb[cb * 64 + l];
  cbox[l] = c;
  carea[l] = (c.z - c.x) * (c.w - c.y);
  __syncthreads();
  u64 bits = 0ull;
  {
#pragma clang fp contract(off)
    for (int m = 0; m < 64; m++) {
      float4 cx = cbox[m];
      float xx1 = fmaxf(rx.x, cx.x);
      float yy1 = fmaxf(rx.y, cx.y);
      float xx2 = fminf(rx.z, cx.z);
      float yy2 = fminf(rx.w, cx.w);
      float inter = fmaxf(xx2 - xx1, 0.0f) * fmaxf(yy2 - yy1, 0.0f);
      float denom = ra + carea[m] - inter + 1e-9f;
      int c_j = cb * 64 + m;
      if (iou_gt(inter, denom) && c_j != r) bits |= (1ull << m);
    }
  }
  mask[(size_t)img * 94 * 6000 + (size_t)cb * 6000 + r] = bits;
  if (cb > rb) {                             // cross-chunk edges: src=r < tgt
    u64 eb2 = bits;
    while (eb2) {
      int m = (int)__ffsll(eb2) - 1;
      eb2 &= eb2 - 1;
      u32 p = atomicAdd(&ecl, 1u);
      if (p < 256u) ebuf[p] = (((u32)(cb * 64 + m)) << 16) | (u32)r;
    }
  }
  __syncthreads();
  u32 n = min(ecl, 256u);
  if (l == 0) {
    if (ecl > 256u) atomicAdd(&ecnt[img], 1000000u);   // overflow -> rescue
    ebase = n ? atomicAdd(&ecnt[img], n) : 0u;
  }
  __syncthreads();
  for (u32 p = l; p < n; p += 64) {
    u32 dp = ebase + p;
    if (dp < ECAP) edges[(size_t)img * ECAP + dp] = ebuf[p];
  }
}

// K5b: rescue — remaining triangle (cb >= max(rb,CW)). No-op when the fast
// scan succeeded for this image (okf[img]==1, the expected case).
__global__ void k_mask_rest(const float4* __restrict__ boxes, u64* __restrict__ mask,
                            const u32* __restrict__ okf) {
  int rb = blockIdx.x, img = blockIdx.y;
  if (okf[img]) return;
  __shared__ float4 cbox[4][64];
  __shared__ float  carea[4][64];
  int t = threadIdx.x;
  int rl = t & 63, g = t >> 6;
  const float4* bb = boxes + (size_t)img * 6016;
  int r = rb * 64 + rl;
  float4 rx = bb[r];
  float ra = (rx.z - rx.x) * (rx.w - rx.y);
  u64* mimg = mask + (size_t)img * 94 * 6000;
  int cb0 = rb > CW ? rb : CW;
  int jmax = (94 - cb0 + 3) >> 2;
  for (int j = 0; j < jmax; j++) {
    int cb = cb0 + g + 4 * j;
    bool act = cb < 94;
    __syncthreads();
    if (act) {
      float4 c = bb[cb * 64 + rl];
      cbox[g][rl] = c;
      carea[g][rl] = (c.z - c.x) * (c.w - c.y);
    }
    __syncthreads();
    if (act) {
#pragma clang fp contract(off)
      u64 bits = 0ull;
      for (int m = 0; m < 64; m++) {
        float4 cx = cbox[g][m];
        float xx1 = fmaxf(rx.x, cx.x);
        float yy1 = fmaxf(rx.y, cx.y);
        float xx2 = fminf(rx.z, cx.z);
        float yy2 = fminf(rx.w, cx.w);
        float inter = fmaxf(xx2 - xx1, 0.0f) * fmaxf(yy2 - yy1, 0.0f);
        float denom = ra + carea[g][m] - inter + 1e-9f;
        int c_j = cb * 64 + m;
        if (iou_gt(inter, denom) && c_j != r) bits |= (1ull << m);
      }
      if (r < PRE) mimg[(size_t)cb * 6000 + r] = bits;
    }
  }
}

// K6a: LEVEL-SYNCHRONOUS greedy NMS (R14, verified): frontier rounds retire
// whole DAG levels; depth ~3 for P(edge)~1e-4. Exact by induction.
__global__ void __launch_bounds__(64, 1) k_scan_fast(
    const u64* __restrict__ mask, const u64* __restrict__ validw,
    const float4* __restrict__ boxes, float4* __restrict__ out,
    u32* __restrict__ okf, const u32* __restrict__ ecnt,
    const u32* __restrict__ edges) {
  __shared__ u64 dw[CW * 64];                // 20,480 B: diag blocks
  __shared__ u64 al[CW], fw[CW], kp[CW], blkX[CW], supX[CW];
  __shared__ u32 eb[ECAP];                   // 16,384 B: edge list
  __shared__ unsigned short list[KOUT];
  int l = threadIdx.x;
  int img = blockIdx.x;
  const u64* mimg = mask + (size_t)img * 94 * 6000;
  for (int c = 0; c < CW; c++) dw[c * 64 + l] = mimg[(size_t)c * 6064 + l];
  u32 E = ecnt[img];
  if (E > (u32)ECAP) { if (l == 0) okf[img] = 0u; return; }
  for (u32 p = l; p < E; p += 64) eb[p] = edges[(size_t)img * ECAP + p];
  if (l < CW) {
    al[l] = validw[img * 96 + l];
    kp[l] = 0ull; blkX[l] = 0ull; supX[l] = 0ull;
  }
  u64 lmask = (1ull << l) - 1ull;            // earlier-in-chunk rows
  bool fail = false;
  for (int round = 0; ; round++) {
    u64 anyv = (l < CW) ? al[l] : 0ull;
#pragma unroll
    for (int off = 32; off >= 1; off >>= 1) anyv |= __shfl_xor(anyv, off);
    if (anyv == 0ull) break;                 // all rows decided
    if (round >= RMAX) { fail = true; break; }
    // cross-chunk blocked-by-alive
    for (u32 p = l; p < E; p += 64) {
      u32 e = eb[p];
      u32 tgt = e >> 16, src = e & 0xFFFFu;
      if ((al[src >> 6] >> (src & 63u)) & 1ull)
        atomicOr(&blkX[tgt >> 6], 1ull << (tgt & 63u));
    }
    // frontier per chunk (iterations independent -> pipelined)
    for (int c = 0; c < CW; c++) {
      u64 a_c = al[c];
      u64 dj = dw[c * 64 + l];
      u64 blkin = __ballot((dj & a_c & lmask) != 0ull);
      if (l == 0) fw[c] = a_c & ~blkin & ~blkX[c];
    }
    // cross-chunk suppressed-by-frontier
    for (u32 p = l; p < E; p += 64) {
      u32 e = eb[p];
      u32 tgt = e >> 16, src = e & 0xFFFFu;
      if ((fw[src >> 6] >> (src & 63u)) & 1ull)
        atomicOr(&supX[tgt >> 6], 1ull << (tgt & 63u));
    }
    // apply: keep frontier, drop suppressed, rest stay alive
    for (int c = 0; c < CW; c++) {
      u64 f_c = fw[c];
      u64 dj = dw[c * 64 + l];
      u64 supin = __ballot((dj & f_c & lmask) != 0ull);
      if (l == 0) {
        kp[c] |= f_c;
        al[c] = al[c] & ~f_c & ~supin & ~supX[c];
      }
    }
    if (l < CW) { blkX[l] = 0ull; supX[l] = 0ull; }
  }
  // prefix popcount over kept words -> ordered positions
  u64 kw_l = (!fail && l < CW) ? kp[l] : 0ull;
  u32 pc = (u32)__popcll(kw_l);
  u32 pre = pc;
  for (int off = 1; off < 64; off <<= 1) {
    u32 v2 = __shfl_up(pre, off);
    if (l >= off) pre += v2;
  }
  u32 tot = __shfl(pre, 63);
  bool ok = !fail && (tot >= (u32)KOUT);
  if (l == 0) okf[img] = ok ? 1u : 0u;
  if (!ok) return;                           // rescue path takes over
  if (l < CW) {                              // expand bits -> ordered list
    u32 b = pre - pc;
    u64 word = kw_l;
    while (word && b < (u32)KOUT) {
      int j = (int)__ffsll(word) - 1;
      word &= word - 1;
      list[b++] = (unsigned short)(l * 64 + j);
    }
  }
  for (int p = l; p < KOUT; p += 64)
    out[(size_t)img * KOUT + p] = boxes[(size_t)img * 6016 + list[p]];
}

// K6b: full-depth rescue scan (94 words, rows 0..5999). No-op when fast
// scan succeeded. Identical semantics to the reference NMS.
__global__ void k_scan_full(const u64* __restrict__ mask, const u64* __restrict__ validw,
                            const float4* __restrict__ boxes, float4* __restrict__ out,
                            const u32* __restrict__ okf) {
  int img = blockIdx.x;
  if (okf[img]) return;
  __shared__ unsigned short kept[KOUT];
  int l = threadIdx.x;
  const u64* vw = validw + img * 96;
  u64 r0 = ~vw[l];
  u64 r1 = (l < MW - 64) ? ~vw[64 + l] : ~0ull;
  const u64* c0p = mask + ((size_t)img * 94 + l) * 6000;
  const u64* c1p = mask + ((size_t)img * 94 + (l < MW - 64 ? 64 + l : 0)) * 6000;

  u64 ca[16], cb[16], na[16], nb2[16];
#pragma unroll
  for (int k = 0; k < 16; k++) {
    ca[k] = c0p[k];
    cb[k] = (l < MW - 64) ? c1p[k] : 0ull;
  }
  int cnt = 0; bool done = false;
  for (int base = 0; base < PRE; base += 16) {
#pragma unroll
    for (int k = 0; k < 16; k++) {
      int rr = base + 16 + k;
      if (rr < PRE) {
        na[k]  = c0p[rr];
        nb2[k] = (l < MW - 64) ? c1p[rr] : 0ull;
      } else { na[k] = 0ull; nb2[k] = 0ull; }
    }
#pragma unroll
    for (int k = 0; k < 16; k++) {
      if (!done) {
        int i = base + k;
        int w = i >> 6;
        u64 wv = (w < 64) ? __shfl(r0, w) : __shfl(r1, w - 64);
        if (!((wv >> (i & 63)) & 1ull)) {
          if (l == 0 && cnt < KOUT) kept[cnt] = (unsigned short)i;
          cnt++;
          r0 |= (l >= w)        ? ca[k] : 0ull;
          r1 |= ((64 + l) >= w) ? cb[k] : 0ull;
          if (cnt >= KOUT) done = true;
        }
      }
    }
    if (done) break;
#pragma unroll
    for (int k = 0; k < 16; k++) { ca[k] = na[k]; cb[k] = nb2[k]; }
  }
  __syncthreads();
  for (int p = l; p < KOUT; p += 64) {
    float4 v = make_float4(0.f, 0.f, 0.f, 0.f);
    if (p < cnt) v = boxes[(size_t)img * 6016 + kept[p]];
    out[(size_t)img * KOUT + p] = v;
  }
}

extern "C" void kernel_launch(void* const* d_in, const int* in_sizes, int n_in,
                              void* d_out, int out_size, void* d_ws, size_t ws_size,
                              hipStream_t stream) {
  const float4* anch  = (const float4*)d_in[0];
  const float2* probs = (const float2*)d_in[1];
  const float4* delt  = (const float4*)d_in[2];
  float4* out = (float4*)d_out;
  char* ws = (char*)d_ws;
  (void)in_sizes; (void)n_in;

  if (ws_size < WS_NEED) {  // not enough scratch: write zeros, bail cleanly
    (void)hipMemsetAsync(d_out, 0, (size_t)out_size * sizeof(float), stream);
    return;
  }

  u64* mask    = (u64*)(ws + OFF_MASK);
  u64* sel     = (u64*)(ws + OFF_SEL);
  float4* bxs  = (float4*)(ws + OFF_BOX);
  u64* validw  = (u64*)(ws + OFF_VAL);
  u32* hist    = (u32*)(ws + OFF_HIST);
  u32* cab     = (u32*)(ws + OFF_CAB);
  u32* bincnt  = (u32*)(ws + OFF_BCNT);
  int* Tarr    = (int*)(ws + OFF_T);
  u32* Marr    = (u32*)(ws + OFF_M);
  u32* okf     = (u32*)(ws + OFF_FLAG);
  u32* ecnt    = (u32*)(ws + OFF_ECNT);
  u32* edges   = (u32*)(ws + OFF_EDG);

  // zero validw+hist+cab+bincnt+T+M+flag+ecnt every call (contiguous)
  (void)hipMemsetAsync(ws + OFF_VAL, 0, 406528, stream);

  dim3 g1(256, B);
  k_hist<<<g1, 256, 0, stream>>>(anch, probs, delt, hist, bxs);
  k_thresh<<<B, 64, 0, stream>>>(hist, Tarr, cab, Marr);
  k_compact<<<g1, 256, 0, stream>>>(anch, probs, delt, Tarr, cab, bincnt, sel);
  dim3 g4(64, B);
  k_rank<<<g4, 256, 0, stream>>>(sel, cab, hist, Marr, anch, delt, bxs, validw);
  dim3 g5(CW * CW, B);
  k_mask<<<g5, 64, 0, stream>>>(bxs, mask, ecnt, edges);
  k_scan_fast<<<B, 64, 0, stream>>>(mask, validw, bxs, out, okf, ecnt, edges);
  dim3 g5b(94, B);
  k_mask_rest<<<g5b, 256, 0, stream>>>(bxs, mask, okf);
  k_scan_full<<<B, 64, 0, stream>>>(mask, validw, bxs, out, okf);
}